// Round 7
// baseline (807.889 us; speedup 1.0000x reference)
//
#include <hip/hip_runtime.h>
#include <cstdint>
#include <cmath>

#define SS 2048
#define HH 1024

typedef __bf16 bf16_t;
typedef __bf16 bf16x8 __attribute__((ext_vector_type(8)));
typedef __bf16 bf16x4 __attribute__((ext_vector_type(4)));
typedef float  f32x4  __attribute__((ext_vector_type(4)));

union U32P { unsigned u; bf16_t h[2]; };

__device__ __forceinline__ void async_load16(const void* g, void* l) {
  __builtin_amdgcn_global_load_lds(
      (__attribute__((address_space(1))) void*)(g),
      (__attribute__((address_space(3))) void*)(l), 16, 0, 0);
}

// ---------------- fp32 -> bf16 convert ------------------------------------
__global__ __launch_bounds__(256) void cvt_kernel(const float* __restrict__ in,
                                                  bf16_t* __restrict__ out) {
  size_t i = (size_t)blockIdx.x * 256 + threadIdx.x;
  f32x4 v = ((const f32x4*)in)[i];
  bf16x4 o;
  o[0] = (bf16_t)v[0]; o[1] = (bf16_t)v[1]; o[2] = (bf16_t)v[2]; o[3] = (bf16_t)v[3];
  ((bf16x4*)out)[i] = o;
}

// ---------------- LayerNorm: fp32 in [4096,1024] -> bf16 out ---------------
__global__ __launch_bounds__(256) void ln_kernel(const float* __restrict__ x,
                                                 const float* __restrict__ w,
                                                 const float* __restrict__ b,
                                                 bf16_t* __restrict__ out) {
  const int row = blockIdx.x;
  const int tid = threadIdx.x;
  const f32x4 v = ((const f32x4*)(x + (size_t)row * HH))[tid];
  float s  = v[0] + v[1] + v[2] + v[3];
  float s2 = v[0]*v[0] + v[1]*v[1] + v[2]*v[2] + v[3]*v[3];
#pragma unroll
  for (int o = 1; o < 64; o <<= 1) { s += __shfl_xor(s, o); s2 += __shfl_xor(s2, o); }
  __shared__ float r1[4], r2[4];
  if ((tid & 63) == 0) { r1[tid >> 6] = s; r2[tid >> 6] = s2; }
  __syncthreads();
  float ts  = r1[0] + r1[1] + r1[2] + r1[3];
  float ts2 = r2[0] + r2[1] + r2[2] + r2[3];
  float mu  = ts * (1.0f / HH);
  float var = ts2 * (1.0f / HH) - mu * mu;
  float rstd = rsqrtf(var + 1e-5f);
  f32x4 wv = ((const f32x4*)w)[tid];
  f32x4 bv = ((const f32x4*)b)[tid];
  bf16x4 o;
#pragma unroll
  for (int j = 0; j < 4; ++j) o[j] = (bf16_t)((v[j] - mu) * rstd * wv[j] + bv[j]);
  ((bf16x4*)(out + (size_t)row * HH))[tid] = o;
}

__device__ __forceinline__ float gelu_f(float x) {
  return 0.5f * x * (1.0f + erff(x * 0.70710678118654752f));
}

// ---- fused residual add: x += p0 + p1 + bias  (p* = bf16 split-K partials) --
__global__ __launch_bounds__(256) void fuse_add(float* __restrict__ x,
                                                const bf16_t* __restrict__ p0,
                                                const bf16_t* __restrict__ p1,
                                                const float* __restrict__ bias) {
  size_t i = (size_t)blockIdx.x * 256 + threadIdx.x;
  f32x4 xv = ((f32x4*)x)[i];
  bf16x4 a = ((const bf16x4*)p0)[i];
  bf16x4 b4 = ((const bf16x4*)p1)[i];
  f32x4 bv = ((const f32x4*)bias)[i & 255];
#pragma unroll
  for (int j = 0; j < 4; ++j) xv[j] += (float)a[j] + (float)b4[j] + bv[j];
  ((f32x4*)x)[i] = xv;
}

// ---------------- GEMM: C[M,N] = A[M,K] * W[N,K]^T + bias, fused epilogues --
template <int EPI>
__global__ __launch_bounds__(256) void gemm_bt(const bf16_t* __restrict__ A,
                                               const bf16_t* __restrict__ W,
                                               const float* __restrict__ bias,
                                               bf16_t* __restrict__ outb,
                                               int M, int N, int K) {
  __shared__ __align__(16) bf16_t As[128 * 64];
  __shared__ __align__(16) bf16_t Bs[128 * 64];
  const int tid = threadIdx.x;
  const int w = tid >> 6, lane = tid & 63;
  const int m16 = lane & 15, quad = lane >> 4;
  const int wm = w & 1, wn = w >> 1;
  const int n0 = blockIdx.x * 128, m0 = blockIdx.y * 128;

  f32x4 acc[4][4];
#pragma unroll
  for (int i = 0; i < 4; ++i)
#pragma unroll
    for (int j = 0; j < 4; ++j) acc[i][j] = (f32x4){0.f, 0.f, 0.f, 0.f};

  int rowi[4], gci[4];
#pragma unroll
  for (int i = 0; i < 4; ++i) {
    int p = (w * 4 + i) * 64 + lane;
    rowi[i] = p >> 3;
    gci[i] = ((lane & 7) ^ (rowi[i] & 7)) * 8;
  }

  for (int kt = 0; kt < K; kt += 64) {
    __syncthreads();
#pragma unroll
    for (int i = 0; i < 4; ++i) {
      async_load16(A + (size_t)(m0 + rowi[i]) * K + kt + gci[i], &As[(w * 4 + i) * 512]);
      async_load16(W + (size_t)(n0 + rowi[i]) * K + kt + gci[i], &Bs[(w * 4 + i) * 512]);
    }
    __syncthreads();
#pragma unroll
    for (int kk = 0; kk < 2; ++kk) {
      bf16x8 af[4], bfv[4];
#pragma unroll
      for (int mi = 0; mi < 4; ++mi) {
        int row = wm * 64 + mi * 16 + m16;
        int cpos = (kk * 4 + quad) ^ (row & 7);
        af[mi] = *(const bf16x8*)&As[row * 64 + cpos * 8];
      }
#pragma unroll
      for (int ni = 0; ni < 4; ++ni) {
        int row = wn * 64 + ni * 16 + m16;
        int cpos = (kk * 4 + quad) ^ (row & 7);
        bfv[ni] = *(const bf16x8*)&Bs[row * 64 + cpos * 8];
      }
#pragma unroll
      for (int mi = 0; mi < 4; ++mi)
#pragma unroll
        for (int ni = 0; ni < 4; ++ni)
          acc[mi][ni] = __builtin_amdgcn_mfma_f32_16x16x32_bf16(af[mi], bfv[ni],
                                                                acc[mi][ni], 0, 0, 0);
    }
  }

#pragma unroll
  for (int ni = 0; ni < 4; ++ni) {
    int col = n0 + wn * 64 + ni * 16 + m16;
    float bv = bias[col];
#pragma unroll
    for (int mi = 0; mi < 4; ++mi) {
      int rowb = m0 + wm * 64 + mi * 16 + quad * 4;
#pragma unroll
      for (int r = 0; r < 4; ++r) {
        size_t idx = (size_t)(rowb + r) * N + col;
        float v = acc[mi][ni][r] + bv;
        if constexpr (EPI == 1) v = gelu_f(v);
        outb[idx] = (bf16_t)v;
      }
    }
  }
}

// ---- QKV GEMM: split epilogue -> qc[b,s,1024], kc/vc[b,h,s,64] -------------
__global__ __launch_bounds__(256) void gemm_qkv(const bf16_t* __restrict__ A,
                                                const bf16_t* __restrict__ W,
                                                const float* __restrict__ bias,
                                                bf16_t* __restrict__ qc,
                                                bf16_t* __restrict__ kc,
                                                bf16_t* __restrict__ vc) {
  const int K = 1024;
  __shared__ __align__(16) bf16_t As[128 * 64];
  __shared__ __align__(16) bf16_t Bs[128 * 64];
  const int tid = threadIdx.x;
  const int w = tid >> 6, lane = tid & 63;
  const int m16 = lane & 15, quad = lane >> 4;
  const int wm = w & 1, wn = w >> 1;
  const int n0 = blockIdx.x * 128, m0 = blockIdx.y * 128;

  f32x4 acc[4][4];
#pragma unroll
  for (int i = 0; i < 4; ++i)
#pragma unroll
    for (int j = 0; j < 4; ++j) acc[i][j] = (f32x4){0.f, 0.f, 0.f, 0.f};

  int rowi[4], gci[4];
#pragma unroll
  for (int i = 0; i < 4; ++i) {
    int p = (w * 4 + i) * 64 + lane;
    rowi[i] = p >> 3;
    gci[i] = ((lane & 7) ^ (rowi[i] & 7)) * 8;
  }

  for (int kt = 0; kt < K; kt += 64) {
    __syncthreads();
#pragma unroll
    for (int i = 0; i < 4; ++i) {
      async_load16(A + (size_t)(m0 + rowi[i]) * K + kt + gci[i], &As[(w * 4 + i) * 512]);
      async_load16(W + (size_t)(n0 + rowi[i]) * K + kt + gci[i], &Bs[(w * 4 + i) * 512]);
    }
    __syncthreads();
#pragma unroll
    for (int kk = 0; kk < 2; ++kk) {
      bf16x8 af[4], bfv[4];
#pragma unroll
      for (int mi = 0; mi < 4; ++mi) {
        int row = wm * 64 + mi * 16 + m16;
        int cpos = (kk * 4 + quad) ^ (row & 7);
        af[mi] = *(const bf16x8*)&As[row * 64 + cpos * 8];
      }
#pragma unroll
      for (int ni = 0; ni < 4; ++ni) {
        int row = wn * 64 + ni * 16 + m16;
        int cpos = (kk * 4 + quad) ^ (row & 7);
        bfv[ni] = *(const bf16x8*)&Bs[row * 64 + cpos * 8];
      }
#pragma unroll
      for (int mi = 0; mi < 4; ++mi)
#pragma unroll
        for (int ni = 0; ni < 4; ++ni)
          acc[mi][ni] = __builtin_amdgcn_mfma_f32_16x16x32_bf16(af[mi], bfv[ni],
                                                                acc[mi][ni], 0, 0, 0);
    }
  }

  const int bb = m0 >> 11;                 // batch index (uniform: 128 | 2048)
  const int sbase = (m0 & 2047) + wm * 64;
#pragma unroll
  for (int ni = 0; ni < 4; ++ni) {
    int col = n0 + wn * 64 + ni * 16 + m16;
    float bv = bias[col];
    int region = col >> 10;                // 0=Q 1=K 2=V
    int h = (col >> 6) & 15, d = col & 63;
#pragma unroll
    for (int mi = 0; mi < 4; ++mi) {
#pragma unroll
      for (int r = 0; r < 4; ++r) {
        int s = sbase + mi * 16 + quad * 4 + r;
        float v = acc[mi][ni][r] + bv;
        if (region == 0) {
          qc[(size_t)(bb * SS + s) * 1024 + col] = (bf16_t)v;
        } else {
          bf16_t* o = (region == 1) ? kc : vc;
          o[((size_t)(bb * 16 + h) * SS + s) * 64 + d] = (bf16_t)v;
        }
      }
    }
  }
}

// ---- split-K=2 GEMM: z-th half of K -> bf16 partial buffer (no bias) -------
__global__ __launch_bounds__(256) void gemm_sk2(const bf16_t* __restrict__ A,
                                                const bf16_t* __restrict__ W,
                                                bf16_t* __restrict__ p0,
                                                bf16_t* __restrict__ p1,
                                                int M, int N, int K) {
  __shared__ __align__(16) bf16_t As[128 * 64];
  __shared__ __align__(16) bf16_t Bs[128 * 64];
  const int tid = threadIdx.x;
  const int w = tid >> 6, lane = tid & 63;
  const int m16 = lane & 15, quad = lane >> 4;
  const int wm = w & 1, wn = w >> 1;
  const int n0 = blockIdx.x * 128, m0 = blockIdx.y * 128;
  const int z = blockIdx.z;
  const int kbeg = z * (K >> 1), kend = kbeg + (K >> 1);
  bf16_t* outb = z ? p1 : p0;

  f32x4 acc[4][4];
#pragma unroll
  for (int i = 0; i < 4; ++i)
#pragma unroll
    for (int j = 0; j < 4; ++j) acc[i][j] = (f32x4){0.f, 0.f, 0.f, 0.f};

  int rowi[4], gci[4];
#pragma unroll
  for (int i = 0; i < 4; ++i) {
    int p = (w * 4 + i) * 64 + lane;
    rowi[i] = p >> 3;
    gci[i] = ((lane & 7) ^ (rowi[i] & 7)) * 8;
  }

  for (int kt = kbeg; kt < kend; kt += 64) {
    __syncthreads();
#pragma unroll
    for (int i = 0; i < 4; ++i) {
      async_load16(A + (size_t)(m0 + rowi[i]) * K + kt + gci[i], &As[(w * 4 + i) * 512]);
      async_load16(W + (size_t)(n0 + rowi[i]) * K + kt + gci[i], &Bs[(w * 4 + i) * 512]);
    }
    __syncthreads();
#pragma unroll
    for (int kk = 0; kk < 2; ++kk) {
      bf16x8 af[4], bfv[4];
#pragma unroll
      for (int mi = 0; mi < 4; ++mi) {
        int row = wm * 64 + mi * 16 + m16;
        int cpos = (kk * 4 + quad) ^ (row & 7);
        af[mi] = *(const bf16x8*)&As[row * 64 + cpos * 8];
      }
#pragma unroll
      for (int ni = 0; ni < 4; ++ni) {
        int row = wn * 64 + ni * 16 + m16;
        int cpos = (kk * 4 + quad) ^ (row & 7);
        bfv[ni] = *(const bf16x8*)&Bs[row * 64 + cpos * 8];
      }
#pragma unroll
      for (int mi = 0; mi < 4; ++mi)
#pragma unroll
        for (int ni = 0; ni < 4; ++ni)
          acc[mi][ni] = __builtin_amdgcn_mfma_f32_16x16x32_bf16(af[mi], bfv[ni],
                                                                acc[mi][ni], 0, 0, 0);
    }
  }

#pragma unroll
  for (int ni = 0; ni < 4; ++ni) {
    int col = n0 + wn * 64 + ni * 16 + m16;
#pragma unroll
    for (int mi = 0; mi < 4; ++mi) {
      int rowb = m0 + wm * 64 + mi * 16 + quad * 4;
#pragma unroll
      for (int r = 0; r < 4; ++r) {
        size_t idx = (size_t)(rowb + r) * N + col;
        outb[idx] = (bf16_t)acc[mi][ni][r];
      }
    }
  }
}

// ---------------- Flash attention v10: 1-wave blocks, no barriers -----------
// v9 post-mortem: throughput arithmetic (11348 chains x ~5600cy / 228K cy
// observed) shows effective concurrency ~1.1 blocks/CU in EVERY round — the
// occupancy counter (13-19%) agrees. The kernel was residency+lockstep-bound;
// all per-tile/scheduling fixes were no-ops. Fix: 64-thread blocks, each wave
// independently owns 16 q-rows x one <=8-tile chunk. grid z = (chunk<<2)|slice.
// LDS 27648 -> 11520 B (single Vt + one Pl slice) => ~14 indep waves/CU, no
// barriers at all (within-wave DS ordering). V load+stage duplicated 4x (all
// L2-resident). setprio kept (m191: helps exactly this structure).
__global__ __launch_bounds__(64) void attn_kernel(const bf16_t* __restrict__ qc,
                                                  const bf16_t* __restrict__ kc,
                                                  const bf16_t* __restrict__ vcp,
                                                  bf16_t* __restrict__ ctx,
                                                  bf16_t* __restrict__ pa0,
                                                  float* __restrict__ pl0,
                                                  bf16_t* __restrict__ pa1,
                                                  float* __restrict__ pl1) {
  const int qt = 31 - blockIdx.y;   // heavy q-tiles first
  const int bh = blockIdx.x;        // b*16 + h
  const int b = bh >> 4, h = bh & 15;
  const int sl4 = blockIdx.z & 3;   // q-slice within the 64-row tile
  const int tid = threadIdx.x;      // 0..63, one wave
  const int m16 = tid & 15, quad = tid >> 4;

  const float slope2 = __builtin_amdgcn_exp2f(-0.70710678118654752f * (float)(h + 1))
                       * 1.4426950408889634f;  // slope_h * log2(e)
  const int wt = (int)((30.0f / slope2 + 63.0f) * 0.015625f);
  const int kt0 = (qt - wt > 0) ? (qt - wt) : 0;
  const int nch = (qt - kt0 + 8) >> 3;          // ceil(T/8)
  const int z = blockIdx.z >> 2;                // k-chunk
  if (z >= nch) return;
  const int ktb = kt0 + z * 8;
  const int kte = (ktb + 7 < qt) ? (ktb + 7) : qt;
  const bool multi = (nch > 1);

  __shared__ __align__(16) bf16_t Vt[64 * 72];  // [d][key], pad 8 (single buf)
  __shared__ __align__(16) bf16_t Pl[16 * 72];  // P[q][key], pad 8

  const int q_abs = qt * 64 + sl4 * 16 + m16;
  float alkb[16];
#pragma unroll
  for (int kn = 0; kn < 4; ++kn)
#pragma unroll
    for (int r = 0; r < 4; ++r)
      alkb[kn * 4 + r] = slope2 * (float)(ktb * 64 + kn * 16 + quad * 4 + r - q_abs);
  const float d64 = slope2 * 64.0f;

  const bf16_t* qbase = qc + (size_t)(b * SS + q_abs) * 1024 + h * 64;
  const bf16x8 bq0 = *(const bf16x8*)(qbase + quad * 8);
  const bf16x8 bq1 = *(const bf16x8*)(qbase + 32 + quad * 8);

  const bf16_t* kbase = kc + ((size_t)(b * 16 + h) * SS + m16) * 64 + quad * 8;
  // V: this wave stages the full 64x64 tile: 2 rows x 32 d per thread
  const int k0 = (tid & 31) * 2, dblk = (tid >> 5) * 32;
  const bf16_t* vsrc = vcp + ((size_t)(b * 16 + h) * SS + k0) * 64 + dblk;
  const int ql = sl4 * 16 + m16;
  constexpr float C = 0.18033688011112042f;  // log2(e)/8

  f32x4 acc[4];
#pragma unroll
  for (int i = 0; i < 4; ++i) acc[i] = (f32x4){0.f, 0.f, 0.f, 0.f};
  float rs_l = 0.f;

  for (int kt = ktb; kt <= kte; ++kt) {
    // issue K + V loads for this tile
    const bf16_t* kb = kbase + (size_t)kt * 4096;
    bf16x8 kf[4][2];
#pragma unroll
    for (int kn = 0; kn < 4; ++kn) {
      kf[kn][0] = *(const bf16x8*)(kb + kn * 1024);
      kf[kn][1] = *(const bf16x8*)(kb + kn * 1024 + 32);
    }
    const bf16_t* vs = vsrc + (size_t)kt * 4096;
    bf16x8 va0[4], va1[4];
#pragma unroll
    for (int c = 0; c < 4; ++c) {
      va0[c] = *(const bf16x8*)(vs + c * 8);
      va1[c] = *(const bf16x8*)(vs + 64 + c * 8);
    }

    __builtin_amdgcn_s_setprio(1);
    // QK^T + softmax (analytic max), pack P -> Pl immediately
    const bool diag = (kt == qt);
#pragma unroll
    for (int kn = 0; kn < 4; ++kn) {
      f32x4 zz = (f32x4){0.f, 0.f, 0.f, 0.f};
      zz = __builtin_amdgcn_mfma_f32_16x16x32_bf16(kf[kn][0], bq0, zz, 0, 0, 0);
      zz = __builtin_amdgcn_mfma_f32_16x16x32_bf16(kf[kn][1], bq1, zz, 0, 0, 0);
      f32x4 ev;
#pragma unroll
      for (int r = 0; r < 4; ++r) {
        float s = fmaf(zz[r], C, alkb[kn * 4 + r]);
        if (diag) {
          int kl = kn * 16 + quad * 4 + r;
          if (kl > ql) s = -INFINITY;
        }
        ev[r] = __builtin_amdgcn_exp2f(s);
        rs_l += ev[r];
      }
      U32P a, c;
      a.h[0] = (bf16_t)ev[0]; a.h[1] = (bf16_t)ev[1];
      c.h[0] = (bf16_t)ev[2]; c.h[1] = (bf16_t)ev[3];
      uint2 pk; pk.x = a.u; pk.y = c.u;
      *(uint2*)&Pl[m16 * 72 + kn * 16 + quad * 4] = pk;
    }
#pragma unroll
    for (int i = 0; i < 16; ++i) alkb[i] += d64;

    // stage V -> Vt (transposed [d][k]); within-wave ordering only
#pragma unroll
    for (int c = 0; c < 4; ++c)
#pragma unroll
      for (int j = 0; j < 8; ++j) {
        U32P pk; pk.h[0] = va0[c][j]; pk.h[1] = va1[c][j];
        *(unsigned*)&Vt[(dblk + c * 8 + j) * 72 + k0] = pk.u;
      }

    // PV from Vt + Pl (compiler inserts lgkmcnt before MFMA use)
    bf16x8 bp0 = *(const bf16x8*)&Pl[m16 * 72 + quad * 8];
    bf16x8 bp1 = *(const bf16x8*)&Pl[m16 * 72 + 32 + quad * 8];
#pragma unroll
    for (int ni = 0; ni < 4; ++ni) {
      bf16x8 av0 = *(const bf16x8*)&Vt[(ni * 16 + m16) * 72 + quad * 8];
      bf16x8 av1 = *(const bf16x8*)&Vt[(ni * 16 + m16) * 72 + 32 + quad * 8];
      acc[ni] = __builtin_amdgcn_mfma_f32_16x16x32_bf16(av0, bp0, acc[ni], 0, 0, 0);
      acc[ni] = __builtin_amdgcn_mfma_f32_16x16x32_bf16(av1, bp1, acc[ni], 0, 0, 0);
    }
    __builtin_amdgcn_s_setprio(0);
  }

  // epilogue: reduce l across quads (same q = m16 column)
  rs_l += __shfl_xor(rs_l, 16);
  rs_l += __shfl_xor(rs_l, 32);

  if (!multi) {
    const float inv_l = 1.0f / rs_l;
    bf16_t* cb = ctx + (size_t)(b * SS + q_abs) * 1024 + h * 64;
#pragma unroll
    for (int ni = 0; ni < 4; ++ni) {
      U32P a, c;
      a.h[0] = (bf16_t)(acc[ni][0] * inv_l); a.h[1] = (bf16_t)(acc[ni][1] * inv_l);
      c.h[0] = (bf16_t)(acc[ni][2] * inv_l); c.h[1] = (bf16_t)(acc[ni][3] * inv_l);
      uint2 pk; pk.x = a.u; pk.y = c.u;
      *(uint2*)(cb + ni * 16 + quad * 4) = pk;
    }
  } else {
    const int sl = (h - 6) * 24 + (qt - 8);                 // [0,240)
    bf16_t* ab = (b ? pa1 : pa0) + (size_t)(sl * 4 + z) * 4096
                 + (size_t)(sl4 * 16 + m16) * 64;
#pragma unroll
    for (int ni = 0; ni < 4; ++ni) {
      U32P a, c;
      a.h[0] = (bf16_t)acc[ni][0]; a.h[1] = (bf16_t)acc[ni][1];
      c.h[0] = (bf16_t)acc[ni][2]; c.h[1] = (bf16_t)acc[ni][3];
      uint2 pk; pk.x = a.u; pk.y = c.u;
      *(uint2*)(ab + ni * 16 + quad * 4) = pk;
    }
    if (quad == 0) (b ? pl1 : pl0)[(sl * 4 + z) * 64 + sl4 * 16 + m16] = rs_l;
  }
}

// ---- combine multi-chunk partials -> ctx (240 slots/batch, h>=6 && qt>=8) --
__global__ __launch_bounds__(256) void attn_norm(const bf16_t* __restrict__ pa0,
                                                 const float* __restrict__ pl0,
                                                 const bf16_t* __restrict__ pa1,
                                                 const float* __restrict__ pl1,
                                                 bf16_t* __restrict__ ctx) {
  const int gs = blockIdx.x;            // [0,480)
  const int b = gs >= 240, sl = b ? gs - 240 : gs;
  const int h = sl / 24 + 6, qt = sl % 24 + 8;
  const bf16_t* pa = b ? pa1 : pa0;
  const float* pl = b ? pl1 : pl0;
  const float slope2 = __builtin_amdgcn_exp2f(-0.70710678118654752f * (float)(h + 1))
                       * 1.4426950408889634f;
  const int wt = (int)((30.0f / slope2 + 63.0f) * 0.015625f);
  const int kt0 = (qt - wt > 0) ? (qt - wt) : 0;
  const int nch = (qt - kt0 + 8) >> 3;

  const int t = threadIdx.x;
  const int q = t >> 2, d0 = (t & 3) << 4;
  const bf16_t* ap = pa + (size_t)sl * 4 * 4096 + (size_t)q * 64 + d0;
  float av[16];
#pragma unroll
  for (int j = 0; j < 16; ++j) av[j] = 0.f;
  float l = 0.f;
  for (int z = 0; z < nch; ++z) {
    bf16x8 a0 = *(const bf16x8*)(ap + (size_t)z * 4096);
    bf16x8 a1 = *(const bf16x8*)(ap + (size_t)z * 4096 + 8);
#pragma unroll
    for (int j = 0; j < 8; ++j) { av[j] += (float)a0[j]; av[8 + j] += (float)a1[j]; }
    l += pl[(sl * 4 + z) * 64 + q];
  }
  const float invl = 1.0f / l;
  bf16_t* cp = ctx + (size_t)(b * SS + qt * 64 + q) * 1024 + h * 64 + d0;
  bf16x8 o0, o1;
#pragma unroll
  for (int j = 0; j < 8; ++j) o0[j] = (bf16_t)(av[j] * invl);
#pragma unroll
  for (int j = 0; j < 8; ++j) o1[j] = (bf16_t)(av[8 + j] * invl);
  *(bf16x8*)cp = o0;
  *(bf16x8*)(cp + 8) = o1;
}

// ---------------------------------------------------------------------------
extern "C" void kernel_launch(void* const* d_in, const int* in_sizes, int n_in,
                              void* d_out, int out_size, void* d_ws, size_t ws_size,
                              hipStream_t stream) {
  const float* hs    = (const float*)d_in[0];
  const float* qkvw  = (const float*)d_in[2];
  const float* qkvb  = (const float*)d_in[3];
  const float* dw    = (const float*)d_in[4];
  const float* db    = (const float*)d_in[5];
  const float* w1    = (const float*)d_in[6];
  const float* b1    = (const float*)d_in[7];
  const float* w2    = (const float*)d_in[8];
  const float* b2    = (const float*)d_in[9];
  const float* ln1w  = (const float*)d_in[10];
  const float* ln1b  = (const float*)d_in[11];
  const float* ln2w  = (const float*)d_in[12];
  const float* ln2b  = (const float*)d_in[13];
  float* x = (float*)d_out;  // residual stream, fp32 [4096,1024]

  char* ws = (char*)d_ws;
  bf16_t* wqc = (bf16_t*)(ws + 0);          // 2*3072*1024 bf16
  bf16_t* wdc = (bf16_t*)(ws + 12582912);   // 2*1024*1024
  bf16_t* w1c = (bf16_t*)(ws + 16777216);   // 2*4096*1024
  bf16_t* w2c = (bf16_t*)(ws + 33554432);   // 2*1024*4096
  bf16_t* hb  = (bf16_t*)(ws + 50331648);   // 4096*1024 (ln out / mlp2 partial0)
  bf16_t* qm  = (bf16_t*)(ws + 58720256);   // big region: qkv out / mlp-mid
  bf16_t* cx  = (bf16_t*)(ws + 92274688);   // 4096*1024 (attn ctx / mlp2 partial1)
  bf16_t* qc = (bf16_t*)(ws + 58720256);    // [2,2048,1024]  8.39MB
  bf16_t* kc = (bf16_t*)(ws + 67108864);    // [2,16,2048,64] 8.39MB
  bf16_t* vc = (bf16_t*)(ws + 75497472);    // [2,16,2048,64] 8.39MB
  bf16_t* dp0 = qm;
  bf16_t* dp1 = qm + (size_t)4096 * 1024;
  bf16_t* pa0 = (bf16_t*)(ws + 50331648);
  float*  pl0 = (float*)(ws + 50331648 + (size_t)240 * 4 * 4096 * 2);
  bf16_t* pa1 = (bf16_t*)(ws + 83886080);
  float*  pl1 = (float*)(ws + 83886080 + (size_t)240 * 4 * 4096 * 2);

  hipMemcpyAsync(x, hs, (size_t)4096 * 1024 * 4, hipMemcpyDeviceToDevice, stream);
  cvt_kernel<<<6144, 256, 0, stream>>>(qkvw, wqc);
  cvt_kernel<<<2048, 256, 0, stream>>>(dw, wdc);
  cvt_kernel<<<8192, 256, 0, stream>>>(w1, w1c);
  cvt_kernel<<<8192, 256, 0, stream>>>(w2, w2c);

  for (int l = 0; l < 2; ++l) {
    ln_kernel<<<4096, 256, 0, stream>>>(x, ln1w + l * 1024, ln1b + l * 1024, hb);
    gemm_qkv<<<dim3(24, 32), 256, 0, stream>>>(hb, wqc + (size_t)l * 3145728,
        qkvb + l * 3072, qc, kc, vc);
    attn_kernel<<<dim3(32, 32, 16), 64, 0, stream>>>(qc, kc, vc, cx,
        pa0, pl0, pa1, pl1);
    attn_norm<<<480, 256, 0, stream>>>(pa0, pl0, pa1, pl1, cx);
    gemm_sk2<<<dim3(8, 32, 2), 256, 0, stream>>>(cx, wdc + (size_t)l * 1048576,
        dp0, dp1, 4096, 1024, 1024);
    fuse_add<<<4096, 256, 0, stream>>>(x, dp0, dp1, db + l * 1024);
    ln_kernel<<<4096, 256, 0, stream>>>(x, ln2w + l * 1024, ln2b + l * 1024, hb);
    gemm_bt<1><<<dim3(32, 32), 256, 0, stream>>>(hb, w1c + (size_t)l * 4194304,
        b1 + l * 4096, qm, 4096, 4096, 1024);
    gemm_sk2<<<dim3(8, 32, 2), 256, 0, stream>>>(qm, w2c + (size_t)l * 4194304,
        hb, cx, 4096, 1024, 4096);
    fuse_add<<<4096, 256, 0, stream>>>(x, hb, cx, b2 + l * 1024);
  }
}

// Round 9
// 711.681 us; speedup vs baseline: 1.1352x; 1.1352x over previous
//
#include <hip/hip_runtime.h>
#include <cstdint>
#include <cmath>

#define SS 2048
#define HH 1024

typedef __bf16 bf16_t;
typedef __bf16 bf16x8 __attribute__((ext_vector_type(8)));
typedef __bf16 bf16x4 __attribute__((ext_vector_type(4)));
typedef float  f32x4  __attribute__((ext_vector_type(4)));

union U32P { unsigned u; bf16_t h[2]; };

__device__ __forceinline__ void async_load16(const void* g, void* l) {
  __builtin_amdgcn_global_load_lds(
      (__attribute__((address_space(1))) void*)(g),
      (__attribute__((address_space(3))) void*)(l), 16, 0, 0);
}

// ---------------- fp32 -> bf16 convert ------------------------------------
__global__ __launch_bounds__(256) void cvt_kernel(const float* __restrict__ in,
                                                  bf16_t* __restrict__ out) {
  size_t i = (size_t)blockIdx.x * 256 + threadIdx.x;
  f32x4 v = ((const f32x4*)in)[i];
  bf16x4 o;
  o[0] = (bf16_t)v[0]; o[1] = (bf16_t)v[1]; o[2] = (bf16_t)v[2]; o[3] = (bf16_t)v[3];
  ((bf16x4*)out)[i] = o;
}

// ---------------- LayerNorm: fp32 in [4096,1024] -> bf16 out ---------------
__global__ __launch_bounds__(256) void ln_kernel(const float* __restrict__ x,
                                                 const float* __restrict__ w,
                                                 const float* __restrict__ b,
                                                 bf16_t* __restrict__ out) {
  const int row = blockIdx.x;
  const int tid = threadIdx.x;
  const f32x4 v = ((const f32x4*)(x + (size_t)row * HH))[tid];
  float s  = v[0] + v[1] + v[2] + v[3];
  float s2 = v[0]*v[0] + v[1]*v[1] + v[2]*v[2] + v[3]*v[3];
#pragma unroll
  for (int o = 1; o < 64; o <<= 1) { s += __shfl_xor(s, o); s2 += __shfl_xor(s2, o); }
  __shared__ float r1[4], r2[4];
  if ((tid & 63) == 0) { r1[tid >> 6] = s; r2[tid >> 6] = s2; }
  __syncthreads();
  float ts  = r1[0] + r1[1] + r1[2] + r1[3];
  float ts2 = r2[0] + r2[1] + r2[2] + r2[3];
  float mu  = ts * (1.0f / HH);
  float var = ts2 * (1.0f / HH) - mu * mu;
  float rstd = rsqrtf(var + 1e-5f);
  f32x4 wv = ((const f32x4*)w)[tid];
  f32x4 bv = ((const f32x4*)b)[tid];
  bf16x4 o;
#pragma unroll
  for (int j = 0; j < 4; ++j) o[j] = (bf16_t)((v[j] - mu) * rstd * wv[j] + bv[j]);
  ((bf16x4*)(out + (size_t)row * HH))[tid] = o;
}

__device__ __forceinline__ float gelu_f(float x) {
  return 0.5f * x * (1.0f + erff(x * 0.70710678118654752f));
}

// ---- fused residual add: x += p0 + p1 + bias  (p* = bf16 split-K partials) --
__global__ __launch_bounds__(256) void fuse_add(float* __restrict__ x,
                                                const bf16_t* __restrict__ p0,
                                                const bf16_t* __restrict__ p1,
                                                const float* __restrict__ bias) {
  size_t i = (size_t)blockIdx.x * 256 + threadIdx.x;
  f32x4 xv = ((f32x4*)x)[i];
  bf16x4 a = ((const bf16x4*)p0)[i];
  bf16x4 b4 = ((const bf16x4*)p1)[i];
  f32x4 bv = ((const f32x4*)bias)[i & 255];
#pragma unroll
  for (int j = 0; j < 4; ++j) xv[j] += (float)a[j] + (float)b4[j] + bv[j];
  ((f32x4*)x)[i] = xv;
}

// ---------------- 256x256-tile GEMM: C = A[M,K] * W[N,K]^T + bias -----------
// Same verified 2-barrier + global_load_lds(16B) + XOR-swizzle structure as
// the 128^2 kernel, scaled to 8 waves (512 thr), per-wave 128x64 output.
// Why: our GEMM pool runs ~452 TF; barrier-stall per K-step is the fixed cost
// and 256^2 amortizes 4x more MFMA per barrier (64 vs 16 per wave) — measured
// refs: 256^2@2-barrier = 792 TF (m112) / 682 TF (m230-V0) vs 128^2 @ short-K
// here. mlp1 grid 16x16=256 blocks = exactly 1/CU; qkv 12x16=192.
// EPI: 0 = bias; 1 = bias + exact gelu.
template <int EPI>
__global__ __launch_bounds__(512, 2) void gemm_bt256(const bf16_t* __restrict__ A,
                                                     const bf16_t* __restrict__ W,
                                                     const float* __restrict__ bias,
                                                     bf16_t* __restrict__ outb,
                                                     int M, int N, int K) {
  __shared__ __align__(16) bf16_t As[256 * 64];   // 32 KB
  __shared__ __align__(16) bf16_t Bs[256 * 64];   // 32 KB
  const int tid = threadIdx.x;
  const int w = tid >> 6, lane = tid & 63;
  const int m16 = lane & 15, quad = lane >> 4;
  const int wm = w >> 2, wn = w & 3;              // 2M x 4N wave grid
  const int n0 = blockIdx.x * 256, m0 = blockIdx.y * 256;

  f32x4 acc[8][4];
#pragma unroll
  for (int i = 0; i < 8; ++i)
#pragma unroll
    for (int j = 0; j < 4; ++j) acc[i][j] = (f32x4){0.f, 0.f, 0.f, 0.f};

  int rowi[4], gci[4];
#pragma unroll
  for (int i = 0; i < 4; ++i) {
    int p = (w * 4 + i) * 64 + lane;     // [0, 2048): 16B-chunk index of tile
    rowi[i] = p >> 3;                    // row 0..255
    gci[i] = ((lane & 7) ^ (rowi[i] & 7)) * 8;   // pre-swizzled global col
  }

  for (int kt = 0; kt < K; kt += 64) {
    __syncthreads();
#pragma unroll
    for (int i = 0; i < 4; ++i) {
      async_load16(A + (size_t)(m0 + rowi[i]) * K + kt + gci[i], &As[(w * 4 + i) * 512]);
      async_load16(W + (size_t)(n0 + rowi[i]) * K + kt + gci[i], &Bs[(w * 4 + i) * 512]);
    }
    __syncthreads();
#pragma unroll
    for (int kk = 0; kk < 2; ++kk) {
      bf16x8 af[8], bfv[4];
#pragma unroll
      for (int mi = 0; mi < 8; ++mi) {
        int row = wm * 128 + mi * 16 + m16;
        int cpos = (kk * 4 + quad) ^ (row & 7);
        af[mi] = *(const bf16x8*)&As[row * 64 + cpos * 8];
      }
#pragma unroll
      for (int ni = 0; ni < 4; ++ni) {
        int row = wn * 64 + ni * 16 + m16;
        int cpos = (kk * 4 + quad) ^ (row & 7);
        bfv[ni] = *(const bf16x8*)&Bs[row * 64 + cpos * 8];
      }
#pragma unroll
      for (int mi = 0; mi < 8; ++mi)
#pragma unroll
        for (int ni = 0; ni < 4; ++ni)
          acc[mi][ni] = __builtin_amdgcn_mfma_f32_16x16x32_bf16(af[mi], bfv[ni],
                                                                acc[mi][ni], 0, 0, 0);
    }
  }

#pragma unroll
  for (int ni = 0; ni < 4; ++ni) {
    int col = n0 + wn * 64 + ni * 16 + m16;
    float bv = bias[col];
#pragma unroll
    for (int mi = 0; mi < 8; ++mi) {
      int rowb = m0 + wm * 128 + mi * 16 + quad * 4;
#pragma unroll
      for (int r = 0; r < 4; ++r) {
        size_t idx = (size_t)(rowb + r) * N + col;
        float v = acc[mi][ni][r] + bv;
        if constexpr (EPI == 1) v = gelu_f(v);
        outb[idx] = (bf16_t)v;
      }
    }
  }
}

// ---- split-K=2 GEMM: z-th half of K -> bf16 partial buffer (no bias) -------
__global__ __launch_bounds__(256) void gemm_sk2(const bf16_t* __restrict__ A,
                                                const bf16_t* __restrict__ W,
                                                bf16_t* __restrict__ p0,
                                                bf16_t* __restrict__ p1,
                                                int M, int N, int K) {
  __shared__ __align__(16) bf16_t As[128 * 64];
  __shared__ __align__(16) bf16_t Bs[128 * 64];
  const int tid = threadIdx.x;
  const int w = tid >> 6, lane = tid & 63;
  const int m16 = lane & 15, quad = lane >> 4;
  const int wm = w & 1, wn = w >> 1;
  const int n0 = blockIdx.x * 128, m0 = blockIdx.y * 128;
  const int z = blockIdx.z;
  const int kbeg = z * (K >> 1), kend = kbeg + (K >> 1);
  bf16_t* outb = z ? p1 : p0;

  f32x4 acc[4][4];
#pragma unroll
  for (int i = 0; i < 4; ++i)
#pragma unroll
    for (int j = 0; j < 4; ++j) acc[i][j] = (f32x4){0.f, 0.f, 0.f, 0.f};

  int rowi[4], gci[4];
#pragma unroll
  for (int i = 0; i < 4; ++i) {
    int p = (w * 4 + i) * 64 + lane;
    rowi[i] = p >> 3;
    gci[i] = ((lane & 7) ^ (rowi[i] & 7)) * 8;
  }

  for (int kt = kbeg; kt < kend; kt += 64) {
    __syncthreads();
#pragma unroll
    for (int i = 0; i < 4; ++i) {
      async_load16(A + (size_t)(m0 + rowi[i]) * K + kt + gci[i], &As[(w * 4 + i) * 512]);
      async_load16(W + (size_t)(n0 + rowi[i]) * K + kt + gci[i], &Bs[(w * 4 + i) * 512]);
    }
    __syncthreads();
#pragma unroll
    for (int kk = 0; kk < 2; ++kk) {
      bf16x8 af[4], bfv[4];
#pragma unroll
      for (int mi = 0; mi < 4; ++mi) {
        int row = wm * 64 + mi * 16 + m16;
        int cpos = (kk * 4 + quad) ^ (row & 7);
        af[mi] = *(const bf16x8*)&As[row * 64 + cpos * 8];
      }
#pragma unroll
      for (int ni = 0; ni < 4; ++ni) {
        int row = wn * 64 + ni * 16 + m16;
        int cpos = (kk * 4 + quad) ^ (row & 7);
        bfv[ni] = *(const bf16x8*)&Bs[row * 64 + cpos * 8];
      }
#pragma unroll
      for (int mi = 0; mi < 4; ++mi)
#pragma unroll
        for (int ni = 0; ni < 4; ++ni)
          acc[mi][ni] = __builtin_amdgcn_mfma_f32_16x16x32_bf16(af[mi], bfv[ni],
                                                                acc[mi][ni], 0, 0, 0);
    }
  }

#pragma unroll
  for (int ni = 0; ni < 4; ++ni) {
    int col = n0 + wn * 64 + ni * 16 + m16;
#pragma unroll
    for (int mi = 0; mi < 4; ++mi) {
      int rowb = m0 + wm * 64 + mi * 16 + quad * 4;
#pragma unroll
      for (int r = 0; r < 4; ++r) {
        size_t idx = (size_t)(rowb + r) * N + col;
        outb[idx] = (bf16_t)acc[mi][ni][r];
      }
    }
  }
}

// ---------------- Flash attention (round-0 verbatim): analytic max ----------
// Reverted: six structural variants (chunking, atomics, barrier semantics,
// layout, reg-banking, 1-wave blocks) all measured >= this version's 90.6us.
__global__ __launch_bounds__(256) void attn_kernel(const bf16_t* __restrict__ qkv,
                                                   bf16_t* __restrict__ ctx) {
  const int qt = 31 - blockIdx.y;   // heavy q-tiles first
  const int bh = blockIdx.x;        // b*16 + h
  const int b = bh >> 4, h = bh & 15;
  const int tid = threadIdx.x;
  const int w = tid >> 6, lane = tid & 63;
  const int m16 = lane & 15, quad = lane >> 4;

  __shared__ __align__(16) bf16_t Vt[2][64 * 72];  // [buf][d][key], pad 8
  __shared__ __align__(16) bf16_t Pl[4][16 * 72];  // per-wave P[q][key], pad 8

  const float slope2 = __builtin_amdgcn_exp2f(-0.70710678118654752f * (float)(h + 1))
                       * 1.4426950408889634f;  // slope_h * log2(e)
  // ALiBi window (tiles): keep tile iff slope2*((qt-kt)*64-63) <= 30
  const int wt = (int)((30.0f / slope2 + 63.0f) * 0.015625f);
  const int kt0 = (qt - wt > 0) ? (qt - wt) : 0;

  const int q_abs = qt * 64 + w * 16 + m16;  // this lane's query position
  float alkb[16];
#pragma unroll
  for (int kn = 0; kn < 4; ++kn)
#pragma unroll
    for (int r = 0; r < 4; ++r)
      alkb[kn * 4 + r] = slope2 * (float)(kt0 * 64 + kn * 16 + quad * 4 + r - q_abs);
  const float d64 = slope2 * 64.0f;

  const int qrow = qt * 64 + w * 16 + m16;
  const bf16_t* qbase = qkv + (size_t)(b * SS + qrow) * 3072 + h * 64;
  const bf16x8 bq0 = *(const bf16x8*)(qbase + quad * 8);
  const bf16x8 bq1 = *(const bf16x8*)(qbase + 32 + quad * 8);

  const bf16_t* kbase = qkv + (size_t)(b * SS + m16) * 3072 + 1024 + h * 64 + quad * 8;
  const int kp2 = (tid & 31) * 2, vd0 = (tid >> 5) * 8;
  const bf16_t* vsrc = qkv + (size_t)(b * SS + kp2) * 3072 + 2048 + h * 64 + vd0;
  const int ql = w * 16 + m16;
  constexpr float C = 0.18033688011112042f;  // log2(e)/8

  f32x4 acc[4];
#pragma unroll
  for (int i = 0; i < 4; ++i) acc[i] = (f32x4){0.f, 0.f, 0.f, 0.f};
  float rs_l = 0.f;  // per-lane partial of l (reduced across quads at end)

  // preload tile kt0: K frags + V staging regs; pre-store V (seen at 1st barrier)
  bf16x8 ak[4][2], v0, v1;
  {
    const bf16_t* kb = kbase + (size_t)kt0 * 64 * 3072;
#pragma unroll
    for (int kn = 0; kn < 4; ++kn) {
      ak[kn][0] = *(const bf16x8*)(kb + (size_t)(kn * 16) * 3072);
      ak[kn][1] = *(const bf16x8*)(kb + (size_t)(kn * 16) * 3072 + 32);
    }
    const bf16_t* vs = vsrc + (size_t)kt0 * 64 * 3072;
    v0 = *(const bf16x8*)(vs);
    v1 = *(const bf16x8*)(vs + 3072);
  }
#pragma unroll
  for (int j = 0; j < 8; ++j) {
    U32P pk; pk.h[0] = v0[j]; pk.h[1] = v1[j];
    *(unsigned*)&Vt[kt0 & 1][(vd0 + j) * 72 + kp2] = pk.u;
  }

  for (int kt = kt0; kt <= qt; ++kt) {
    __syncthreads();  // Vt[kt&1] writes now visible

    bf16x8 nk[4][2], nv0 = v0, nv1 = v1;
    if (kt < qt) {  // issue next-tile loads; consumed a full tile later
      const bf16_t* kb = kbase + (size_t)(kt + 1) * 64 * 3072;
#pragma unroll
      for (int kn = 0; kn < 4; ++kn) {
        nk[kn][0] = *(const bf16x8*)(kb + (size_t)(kn * 16) * 3072);
        nk[kn][1] = *(const bf16x8*)(kb + (size_t)(kn * 16) * 3072 + 32);
      }
      const bf16_t* nsrc = vsrc + (size_t)(kt + 1) * 64 * 3072;
      nv0 = *(const bf16x8*)(nsrc);
      nv1 = *(const bf16x8*)(nsrc + 3072);
    } else {
#pragma unroll
      for (int kn = 0; kn < 4; ++kn) { nk[kn][0] = ak[kn][0]; nk[kn][1] = ak[kn][1]; }
    }

    // S^T tile from pre-loaded K regs; softmax with analytic max (no shuffles)
    float p[16];
    const bool diag = (kt == qt);
#pragma unroll
    for (int kn = 0; kn < 4; ++kn) {
      f32x4 z = (f32x4){0.f, 0.f, 0.f, 0.f};
      z = __builtin_amdgcn_mfma_f32_16x16x32_bf16(ak[kn][0], bq0, z, 0, 0, 0);
      z = __builtin_amdgcn_mfma_f32_16x16x32_bf16(ak[kn][1], bq1, z, 0, 0, 0);
#pragma unroll
      for (int r = 0; r < 4; ++r) {
        float s = fmaf(z[r], C, alkb[kn * 4 + r]);
        if (diag) {
          int kl = kn * 16 + quad * 4 + r;
          if (kl > ql) s = -INFINITY;
        }
        float e = __builtin_amdgcn_exp2f(s);
        p[kn * 4 + r] = e;
        rs_l += e;
      }
    }
#pragma unroll
    for (int i = 0; i < 16; ++i) alkb[i] += d64;

#pragma unroll
    for (int kn = 0; kn < 4; ++kn) {
      U32P a, c;
      a.h[0] = (bf16_t)p[kn * 4 + 0]; a.h[1] = (bf16_t)p[kn * 4 + 1];
      c.h[0] = (bf16_t)p[kn * 4 + 2]; c.h[1] = (bf16_t)p[kn * 4 + 3];
      uint2 pk; pk.x = a.u; pk.y = c.u;
      *(uint2*)&Pl[w][m16 * 72 + kn * 16 + quad * 4] = pk;
    }
    const bf16_t* vt = &Vt[kt & 1][0];
    bf16x8 bp0 = *(const bf16x8*)&Pl[w][m16 * 72 + quad * 8];
    bf16x8 bp1 = *(const bf16x8*)&Pl[w][m16 * 72 + 32 + quad * 8];
#pragma unroll
    for (int ni = 0; ni < 4; ++ni) {
      bf16x8 av0 = *(const bf16x8*)&vt[(ni * 16 + m16) * 72 + quad * 8];
      bf16x8 av1 = *(const bf16x8*)&vt[(ni * 16 + m16) * 72 + 32 + quad * 8];
      acc[ni] = __builtin_amdgcn_mfma_f32_16x16x32_bf16(av0, bp0, acc[ni], 0, 0, 0);
      acc[ni] = __builtin_amdgcn_mfma_f32_16x16x32_bf16(av1, bp1, acc[ni], 0, 0, 0);
    }

    if (kt < qt) {  // stage next V into the other buffer
#pragma unroll
      for (int j = 0; j < 8; ++j) {
        U32P pk; pk.h[0] = nv0[j]; pk.h[1] = nv1[j];
        *(unsigned*)&Vt[(kt + 1) & 1][(vd0 + j) * 72 + kp2] = pk.u;
      }
    }
#pragma unroll
    for (int kn = 0; kn < 4; ++kn) { ak[kn][0] = nk[kn][0]; ak[kn][1] = nk[kn][1]; }
    v0 = nv0; v1 = nv1;
  }

  // epilogue: reduce l across quads (same q = m16 column), then write O
  rs_l += __shfl_xor(rs_l, 16);
  rs_l += __shfl_xor(rs_l, 32);
  const float inv_l = 1.0f / rs_l;
  bf16_t* cb = ctx + (size_t)(b * SS + qt * 64 + w * 16 + m16) * 1024 + h * 64;
#pragma unroll
  for (int ni = 0; ni < 4; ++ni) {
    U32P a, c;
    a.h[0] = (bf16_t)(acc[ni][0] * inv_l); a.h[1] = (bf16_t)(acc[ni][1] * inv_l);
    c.h[0] = (bf16_t)(acc[ni][2] * inv_l); c.h[1] = (bf16_t)(acc[ni][3] * inv_l);
    uint2 pk; pk.x = a.u; pk.y = c.u;
    *(uint2*)(cb + ni * 16 + quad * 4) = pk;
  }
}

// ---------------------------------------------------------------------------
extern "C" void kernel_launch(void* const* d_in, const int* in_sizes, int n_in,
                              void* d_out, int out_size, void* d_ws, size_t ws_size,
                              hipStream_t stream) {
  const float* hs    = (const float*)d_in[0];
  const float* qkvw  = (const float*)d_in[2];
  const float* qkvb  = (const float*)d_in[3];
  const float* dw    = (const float*)d_in[4];
  const float* db    = (const float*)d_in[5];
  const float* w1    = (const float*)d_in[6];
  const float* b1    = (const float*)d_in[7];
  const float* w2    = (const float*)d_in[8];
  const float* b2    = (const float*)d_in[9];
  const float* ln1w  = (const float*)d_in[10];
  const float* ln1b  = (const float*)d_in[11];
  const float* ln2w  = (const float*)d_in[12];
  const float* ln2b  = (const float*)d_in[13];
  float* x = (float*)d_out;  // residual stream, fp32 [4096,1024]

  char* ws = (char*)d_ws;
  bf16_t* wqc = (bf16_t*)(ws + 0);          // 2*3072*1024 bf16
  bf16_t* wdc = (bf16_t*)(ws + 12582912);   // 2*1024*1024
  bf16_t* w1c = (bf16_t*)(ws + 16777216);   // 2*4096*1024
  bf16_t* w2c = (bf16_t*)(ws + 33554432);   // 2*1024*4096
  bf16_t* hb  = (bf16_t*)(ws + 50331648);   // 4096*1024 (ln out / mlp2 partial0)
  bf16_t* qm  = (bf16_t*)(ws + 58720256);   // qkv / mlp-mid / dense partials
  bf16_t* cx  = (bf16_t*)(ws + 92274688);   // 4096*1024 (attn ctx / mlp2 partial1)
  bf16_t* dp0 = qm;                          // dense partials alias qm (free then)
  bf16_t* dp1 = qm + (size_t)4096 * 1024;

  hipMemcpyAsync(x, hs, (size_t)4096 * 1024 * 4, hipMemcpyDeviceToDevice, stream);
  cvt_kernel<<<6144, 256, 0, stream>>>(qkvw, wqc);
  cvt_kernel<<<2048, 256, 0, stream>>>(dw, wdc);
  cvt_kernel<<<8192, 256, 0, stream>>>(w1, w1c);
  cvt_kernel<<<8192, 256, 0, stream>>>(w2, w2c);

  for (int l = 0; l < 2; ++l) {
    ln_kernel<<<4096, 256, 0, stream>>>(x, ln1w + l * 1024, ln1b + l * 1024, hb);
    // qkv: 256^2 tile, grid 12x16 = 192 blocks
    gemm_bt256<0><<<dim3(12, 16), 512, 0, stream>>>(hb, wqc + (size_t)l * 3145728,
        qkvb + l * 3072, qm, 4096, 3072, 1024);
    attn_kernel<<<dim3(32, 32), 256, 0, stream>>>(qm, cx);
    // dense: split-K=2 -> bf16 partials in qm region, then fused add
    gemm_sk2<<<dim3(8, 32, 2), 256, 0, stream>>>(cx, wdc + (size_t)l * 1048576,
        dp0, dp1, 4096, 1024, 1024);
    fuse_add<<<4096, 256, 0, stream>>>(x, dp0, dp1, db + l * 1024);
    ln_kernel<<<4096, 256, 0, stream>>>(x, ln2w + l * 1024, ln2b + l * 1024, hb);
    // mlp1: 256^2 tile, grid 16x16 = 256 blocks (exactly 1/CU), gelu epilogue
    gemm_bt256<1><<<dim3(16, 16), 512, 0, stream>>>(hb, w1c + (size_t)l * 4194304,
        b1 + l * 4096, qm, 4096, 4096, 1024);
    // mlp2: split-K=2 -> partials in hb & cx (both free here), then fused add
    gemm_sk2<<<dim3(8, 32, 2), 256, 0, stream>>>(qm, w2c + (size_t)l * 4194304,
        hb, cx, 4096, 1024, 4096);
    fuse_add<<<4096, 256, 0, stream>>>(x, hb, cx, b2 + l * 1024);
  }
}

// Round 10
// 674.824 us; speedup vs baseline: 1.1972x; 1.0546x over previous
//
#include <hip/hip_runtime.h>
#include <cstdint>
#include <cmath>

#define SS 2048
#define HH 1024

typedef __bf16 bf16_t;
typedef __bf16 bf16x8 __attribute__((ext_vector_type(8)));
typedef __bf16 bf16x4 __attribute__((ext_vector_type(4)));
typedef float  f32x4  __attribute__((ext_vector_type(4)));

union U32P { unsigned u; bf16_t h[2]; };

__device__ __forceinline__ void async_load16(const void* g, void* l) {
  __builtin_amdgcn_global_load_lds(
      (__attribute__((address_space(1))) void*)(g),
      (__attribute__((address_space(3))) void*)(l), 16, 0, 0);
}

// ---------------- fp32 -> bf16 convert ------------------------------------
__global__ __launch_bounds__(256) void cvt_kernel(const float* __restrict__ in,
                                                  bf16_t* __restrict__ out) {
  size_t i = (size_t)blockIdx.x * 256 + threadIdx.x;
  f32x4 v = ((const f32x4*)in)[i];
  bf16x4 o;
  o[0] = (bf16_t)v[0]; o[1] = (bf16_t)v[1]; o[2] = (bf16_t)v[2]; o[3] = (bf16_t)v[3];
  ((bf16x4*)out)[i] = o;
}

// ---------------- LayerNorm: fp32 in [4096,1024] -> bf16 out ---------------
__global__ __launch_bounds__(256) void ln_kernel(const float* __restrict__ x,
                                                 const float* __restrict__ w,
                                                 const float* __restrict__ b,
                                                 bf16_t* __restrict__ out) {
  const int row = blockIdx.x;
  const int tid = threadIdx.x;
  const f32x4 v = ((const f32x4*)(x + (size_t)row * HH))[tid];
  float s  = v[0] + v[1] + v[2] + v[3];
  float s2 = v[0]*v[0] + v[1]*v[1] + v[2]*v[2] + v[3]*v[3];
#pragma unroll
  for (int o = 1; o < 64; o <<= 1) { s += __shfl_xor(s, o); s2 += __shfl_xor(s2, o); }
  __shared__ float r1[4], r2[4];
  if ((tid & 63) == 0) { r1[tid >> 6] = s; r2[tid >> 6] = s2; }
  __syncthreads();
  float ts  = r1[0] + r1[1] + r1[2] + r1[3];
  float ts2 = r2[0] + r2[1] + r2[2] + r2[3];
  float mu  = ts * (1.0f / HH);
  float var = ts2 * (1.0f / HH) - mu * mu;
  float rstd = rsqrtf(var + 1e-5f);
  f32x4 wv = ((const f32x4*)w)[tid];
  f32x4 bv = ((const f32x4*)b)[tid];
  bf16x4 o;
#pragma unroll
  for (int j = 0; j < 4; ++j) o[j] = (bf16_t)((v[j] - mu) * rstd * wv[j] + bv[j]);
  ((bf16x4*)(out + (size_t)row * HH))[tid] = o;
}

__device__ __forceinline__ float gelu_f(float x) {
  return 0.5f * x * (1.0f + erff(x * 0.70710678118654752f));
}

// ---- fused residual add: x += p0 + p1 + bias (final use, no trailing LN) ---
__global__ __launch_bounds__(256) void fuse_add(float* __restrict__ x,
                                                const bf16_t* __restrict__ p0,
                                                const bf16_t* __restrict__ p1,
                                                const float* __restrict__ bias) {
  size_t i = (size_t)blockIdx.x * 256 + threadIdx.x;
  f32x4 xv = ((f32x4*)x)[i];
  bf16x4 a = ((const bf16x4*)p0)[i];
  bf16x4 b4 = ((const bf16x4*)p1)[i];
  f32x4 bv = ((const f32x4*)bias)[i & 255];
#pragma unroll
  for (int j = 0; j < 4; ++j) xv[j] += (float)a[j] + (float)b4[j] + bv[j];
  ((f32x4*)x)[i] = xv;
}

// ---- fused residual add + LayerNorm: x += p0+p1+bias; out = LN(x) ----------
// Each block owns exactly one row (256 thr x 4 f32). Saves a full x re-read
// + one launch vs the fuse_add; ln pair. Safe when out aliases p0: all reads
// happen before the reduction barrier, writes after.
__global__ __launch_bounds__(256) void fuse_add_ln(float* __restrict__ x,
                                                   const bf16_t* __restrict__ p0,
                                                   const bf16_t* __restrict__ p1,
                                                   const float* __restrict__ bias,
                                                   const float* __restrict__ lw,
                                                   const float* __restrict__ lb,
                                                   bf16_t* __restrict__ out) {
  const int row = blockIdx.x;
  const int tid = threadIdx.x;
  const size_t i = (size_t)row * 256 + tid;
  f32x4 xv = ((f32x4*)x)[i];
  bf16x4 a = ((const bf16x4*)p0)[i];
  bf16x4 b4 = ((const bf16x4*)p1)[i];
  f32x4 bv = ((const f32x4*)bias)[tid];
#pragma unroll
  for (int j = 0; j < 4; ++j) xv[j] += (float)a[j] + (float)b4[j] + bv[j];
  ((f32x4*)x)[i] = xv;
  float s  = xv[0] + xv[1] + xv[2] + xv[3];
  float s2 = xv[0]*xv[0] + xv[1]*xv[1] + xv[2]*xv[2] + xv[3]*xv[3];
#pragma unroll
  for (int o = 1; o < 64; o <<= 1) { s += __shfl_xor(s, o); s2 += __shfl_xor(s2, o); }
  __shared__ float r1[4], r2[4];
  if ((tid & 63) == 0) { r1[tid >> 6] = s; r2[tid >> 6] = s2; }
  __syncthreads();
  float ts  = r1[0] + r1[1] + r1[2] + r1[3];
  float ts2 = r2[0] + r2[1] + r2[2] + r2[3];
  float mu  = ts * (1.0f / HH);
  float var = ts2 * (1.0f / HH) - mu * mu;
  float rstd = rsqrtf(var + 1e-5f);
  f32x4 wv  = ((const f32x4*)lw)[tid];
  f32x4 lbv = ((const f32x4*)lb)[tid];
  bf16x4 o;
#pragma unroll
  for (int j = 0; j < 4; ++j) o[j] = (bf16_t)((xv[j] - mu) * rstd * wv[j] + lbv[j]);
  ((bf16x4*)(out + (size_t)row * HH))[tid] = o;
}

// ---------------- 2-phase GEMM: C = A[M,K] * W[N,K]^T + bias ----------------
// T3 "minimum 2-phase" (catalog, refcheck'd 622-682 TF at K=1024-class): issue
// next-tile global_load_lds BEFORE computing current tile; ONE __syncthreads
// per K-step (its vmcnt(0) drain waits on loads that overlapped a full compute
// phase). Old structure (stage -> drain -> compute) exposed full load latency
// every K-step -> ~460 TF effective pool. LDS 64KB (2 bufs) -> 2 blocks/CU.
// EPI: 0 = bias; 1 = bias + exact gelu.
template <int EPI>
__global__ __launch_bounds__(256) void gemm_bt(const bf16_t* __restrict__ A,
                                               const bf16_t* __restrict__ W,
                                               const float* __restrict__ bias,
                                               bf16_t* __restrict__ outb,
                                               int M, int N, int K) {
  __shared__ __align__(16) bf16_t As[2][128 * 64];
  __shared__ __align__(16) bf16_t Bs[2][128 * 64];
  const int tid = threadIdx.x;
  const int w = tid >> 6, lane = tid & 63;
  const int m16 = lane & 15, quad = lane >> 4;
  const int wm = w & 1, wn = w >> 1;
  const int n0 = blockIdx.x * 128, m0 = blockIdx.y * 128;

  f32x4 acc[4][4];
#pragma unroll
  for (int i = 0; i < 4; ++i)
#pragma unroll
    for (int j = 0; j < 4; ++j) acc[i][j] = (f32x4){0.f, 0.f, 0.f, 0.f};

  int rowi[4], gci[4];
#pragma unroll
  for (int i = 0; i < 4; ++i) {
    int p = (w * 4 + i) * 64 + lane;
    rowi[i] = p >> 3;
    gci[i] = ((lane & 7) ^ (rowi[i] & 7)) * 8;
  }

  // prologue: stage tile 0 -> buf 0
#pragma unroll
  for (int i = 0; i < 4; ++i) {
    async_load16(A + (size_t)(m0 + rowi[i]) * K + gci[i], &As[0][(w * 4 + i) * 512]);
    async_load16(W + (size_t)(n0 + rowi[i]) * K + gci[i], &Bs[0][(w * 4 + i) * 512]);
  }

  const int NT = K >> 6;
  for (int t = 0; t < NT; ++t) {
    const int cur = t & 1;
    __syncthreads();   // vmcnt(0) drain: tile t resident; buf cur^1 free
    if (t + 1 < NT) {
      const int kt = (t + 1) << 6;
#pragma unroll
      for (int i = 0; i < 4; ++i) {
        async_load16(A + (size_t)(m0 + rowi[i]) * K + kt + gci[i],
                     &As[cur ^ 1][(w * 4 + i) * 512]);
        async_load16(W + (size_t)(n0 + rowi[i]) * K + kt + gci[i],
                     &Bs[cur ^ 1][(w * 4 + i) * 512]);
      }
    }
#pragma unroll
    for (int kk = 0; kk < 2; ++kk) {
      bf16x8 af[4], bfv[4];
#pragma unroll
      for (int mi = 0; mi < 4; ++mi) {
        int row = wm * 64 + mi * 16 + m16;
        int cpos = (kk * 4 + quad) ^ (row & 7);
        af[mi] = *(const bf16x8*)&As[cur][row * 64 + cpos * 8];
      }
#pragma unroll
      for (int ni = 0; ni < 4; ++ni) {
        int row = wn * 64 + ni * 16 + m16;
        int cpos = (kk * 4 + quad) ^ (row & 7);
        bfv[ni] = *(const bf16x8*)&Bs[cur][row * 64 + cpos * 8];
      }
#pragma unroll
      for (int mi = 0; mi < 4; ++mi)
#pragma unroll
        for (int ni = 0; ni < 4; ++ni)
          acc[mi][ni] = __builtin_amdgcn_mfma_f32_16x16x32_bf16(af[mi], bfv[ni],
                                                                acc[mi][ni], 0, 0, 0);
    }
  }

#pragma unroll
  for (int ni = 0; ni < 4; ++ni) {
    int col = n0 + wn * 64 + ni * 16 + m16;
    float bv = bias[col];
#pragma unroll
    for (int mi = 0; mi < 4; ++mi) {
      int rowb = m0 + wm * 64 + mi * 16 + quad * 4;
#pragma unroll
      for (int r = 0; r < 4; ++r) {
        size_t idx = (size_t)(rowb + r) * N + col;
        float v = acc[mi][ni][r] + bv;
        if constexpr (EPI == 1) v = gelu_f(v);
        outb[idx] = (bf16_t)v;
      }
    }
  }
}

// ---- 2-phase split-K=2 GEMM: z-th half of K -> bf16 partial (no bias) ------
__global__ __launch_bounds__(256) void gemm_sk2(const bf16_t* __restrict__ A,
                                                const bf16_t* __restrict__ W,
                                                bf16_t* __restrict__ p0,
                                                bf16_t* __restrict__ p1,
                                                int M, int N, int K) {
  __shared__ __align__(16) bf16_t As[2][128 * 64];
  __shared__ __align__(16) bf16_t Bs[2][128 * 64];
  const int tid = threadIdx.x;
  const int w = tid >> 6, lane = tid & 63;
  const int m16 = lane & 15, quad = lane >> 4;
  const int wm = w & 1, wn = w >> 1;
  const int n0 = blockIdx.x * 128, m0 = blockIdx.y * 128;
  const int z = blockIdx.z;
  const int kbeg = z * (K >> 1);
  bf16_t* outb = z ? p1 : p0;

  f32x4 acc[4][4];
#pragma unroll
  for (int i = 0; i < 4; ++i)
#pragma unroll
    for (int j = 0; j < 4; ++j) acc[i][j] = (f32x4){0.f, 0.f, 0.f, 0.f};

  int rowi[4], gci[4];
#pragma unroll
  for (int i = 0; i < 4; ++i) {
    int p = (w * 4 + i) * 64 + lane;
    rowi[i] = p >> 3;
    gci[i] = ((lane & 7) ^ (rowi[i] & 7)) * 8;
  }

  // prologue: stage tile kbeg -> buf 0
#pragma unroll
  for (int i = 0; i < 4; ++i) {
    async_load16(A + (size_t)(m0 + rowi[i]) * K + kbeg + gci[i], &As[0][(w * 4 + i) * 512]);
    async_load16(W + (size_t)(n0 + rowi[i]) * K + kbeg + gci[i], &Bs[0][(w * 4 + i) * 512]);
  }

  const int NT = K >> 7;   // (K/2)/64 tiles
  for (int t = 0; t < NT; ++t) {
    const int cur = t & 1;
    __syncthreads();
    if (t + 1 < NT) {
      const int kt = kbeg + ((t + 1) << 6);
#pragma unroll
      for (int i = 0; i < 4; ++i) {
        async_load16(A + (size_t)(m0 + rowi[i]) * K + kt + gci[i],
                     &As[cur ^ 1][(w * 4 + i) * 512]);
        async_load16(W + (size_t)(n0 + rowi[i]) * K + kt + gci[i],
                     &Bs[cur ^ 1][(w * 4 + i) * 512]);
      }
    }
#pragma unroll
    for (int kk = 0; kk < 2; ++kk) {
      bf16x8 af[4], bfv[4];
#pragma unroll
      for (int mi = 0; mi < 4; ++mi) {
        int row = wm * 64 + mi * 16 + m16;
        int cpos = (kk * 4 + quad) ^ (row & 7);
        af[mi] = *(const bf16x8*)&As[cur][row * 64 + cpos * 8];
      }
#pragma unroll
      for (int ni = 0; ni < 4; ++ni) {
        int row = wn * 64 + ni * 16 + m16;
        int cpos = (kk * 4 + quad) ^ (row & 7);
        bfv[ni] = *(const bf16x8*)&Bs[cur][row * 64 + cpos * 8];
      }
#pragma unroll
      for (int mi = 0; mi < 4; ++mi)
#pragma unroll
        for (int ni = 0; ni < 4; ++ni)
          acc[mi][ni] = __builtin_amdgcn_mfma_f32_16x16x32_bf16(af[mi], bfv[ni],
                                                                acc[mi][ni], 0, 0, 0);
    }
  }

#pragma unroll
  for (int ni = 0; ni < 4; ++ni) {
    int col = n0 + wn * 64 + ni * 16 + m16;
#pragma unroll
    for (int mi = 0; mi < 4; ++mi) {
      int rowb = m0 + wm * 64 + mi * 16 + quad * 4;
#pragma unroll
      for (int r = 0; r < 4; ++r) {
        size_t idx = (size_t)(rowb + r) * N + col;
        outb[idx] = (bf16_t)acc[mi][ni][r];
      }
    }
  }
}

// ---------------- Flash attention (round-0 verbatim): analytic max ----------
// Kept: six structural variants all measured >= this version's 90.6us.
__global__ __launch_bounds__(256) void attn_kernel(const bf16_t* __restrict__ qkv,
                                                   bf16_t* __restrict__ ctx) {
  const int qt = 31 - blockIdx.y;   // heavy q-tiles first
  const int bh = blockIdx.x;        // b*16 + h
  const int b = bh >> 4, h = bh & 15;
  const int tid = threadIdx.x;
  const int w = tid >> 6, lane = tid & 63;
  const int m16 = lane & 15, quad = lane >> 4;

  __shared__ __align__(16) bf16_t Vt[2][64 * 72];  // [buf][d][key], pad 8
  __shared__ __align__(16) bf16_t Pl[4][16 * 72];  // per-wave P[q][key], pad 8

  const float slope2 = __builtin_amdgcn_exp2f(-0.70710678118654752f * (float)(h + 1))
                       * 1.4426950408889634f;  // slope_h * log2(e)
  // ALiBi window (tiles): keep tile iff slope2*((qt-kt)*64-63) <= 30
  const int wt = (int)((30.0f / slope2 + 63.0f) * 0.015625f);
  const int kt0 = (qt - wt > 0) ? (qt - wt) : 0;

  const int q_abs = qt * 64 + w * 16 + m16;  // this lane's query position
  float alkb[16];
#pragma unroll
  for (int kn = 0; kn < 4; ++kn)
#pragma unroll
    for (int r = 0; r < 4; ++r)
      alkb[kn * 4 + r] = slope2 * (float)(kt0 * 64 + kn * 16 + quad * 4 + r - q_abs);
  const float d64 = slope2 * 64.0f;

  const int qrow = qt * 64 + w * 16 + m16;
  const bf16_t* qbase = qkv + (size_t)(b * SS + qrow) * 3072 + h * 64;
  const bf16x8 bq0 = *(const bf16x8*)(qbase + quad * 8);
  const bf16x8 bq1 = *(const bf16x8*)(qbase + 32 + quad * 8);

  const bf16_t* kbase = qkv + (size_t)(b * SS + m16) * 3072 + 1024 + h * 64 + quad * 8;
  const int kp2 = (tid & 31) * 2, vd0 = (tid >> 5) * 8;
  const bf16_t* vsrc = qkv + (size_t)(b * SS + kp2) * 3072 + 2048 + h * 64 + vd0;
  const int ql = w * 16 + m16;
  constexpr float C = 0.18033688011112042f;  // log2(e)/8

  f32x4 acc[4];
#pragma unroll
  for (int i = 0; i < 4; ++i) acc[i] = (f32x4){0.f, 0.f, 0.f, 0.f};
  float rs_l = 0.f;  // per-lane partial of l (reduced across quads at end)

  // preload tile kt0: K frags + V staging regs; pre-store V (seen at 1st barrier)
  bf16x8 ak[4][2], v0, v1;
  {
    const bf16_t* kb = kbase + (size_t)kt0 * 64 * 3072;
#pragma unroll
    for (int kn = 0; kn < 4; ++kn) {
      ak[kn][0] = *(const bf16x8*)(kb + (size_t)(kn * 16) * 3072);
      ak[kn][1] = *(const bf16x8*)(kb + (size_t)(kn * 16) * 3072 + 32);
    }
    const bf16_t* vs = vsrc + (size_t)kt0 * 64 * 3072;
    v0 = *(const bf16x8*)(vs);
    v1 = *(const bf16x8*)(vs + 3072);
  }
#pragma unroll
  for (int j = 0; j < 8; ++j) {
    U32P pk; pk.h[0] = v0[j]; pk.h[1] = v1[j];
    *(unsigned*)&Vt[kt0 & 1][(vd0 + j) * 72 + kp2] = pk.u;
  }

  for (int kt = kt0; kt <= qt; ++kt) {
    __syncthreads();  // Vt[kt&1] writes now visible

    bf16x8 nk[4][2], nv0 = v0, nv1 = v1;
    if (kt < qt) {  // issue next-tile loads; consumed a full tile later
      const bf16_t* kb = kbase + (size_t)(kt + 1) * 64 * 3072;
#pragma unroll
      for (int kn = 0; kn < 4; ++kn) {
        nk[kn][0] = *(const bf16x8*)(kb + (size_t)(kn * 16) * 3072);
        nk[kn][1] = *(const bf16x8*)(kb + (size_t)(kn * 16) * 3072 + 32);
      }
      const bf16_t* nsrc = vsrc + (size_t)(kt + 1) * 64 * 3072;
      nv0 = *(const bf16x8*)(nsrc);
      nv1 = *(const bf16x8*)(nsrc + 3072);
    } else {
#pragma unroll
      for (int kn = 0; kn < 4; ++kn) { nk[kn][0] = ak[kn][0]; nk[kn][1] = ak[kn][1]; }
    }

    // S^T tile from pre-loaded K regs; softmax with analytic max (no shuffles)
    float p[16];
    const bool diag = (kt == qt);
#pragma unroll
    for (int kn = 0; kn < 4; ++kn) {
      f32x4 z = (f32x4){0.f, 0.f, 0.f, 0.f};
      z = __builtin_amdgcn_mfma_f32_16x16x32_bf16(ak[kn][0], bq0, z, 0, 0, 0);
      z = __builtin_amdgcn_mfma_f32_16x16x32_bf16(ak[kn][1], bq1, z, 0, 0, 0);
#pragma unroll
      for (int r = 0; r < 4; ++r) {
        float s = fmaf(z[r], C, alkb[kn * 4 + r]);
        if (diag) {
          int kl = kn * 16 + quad * 4 + r;
          if (kl > ql) s = -INFINITY;
        }
        float e = __builtin_amdgcn_exp2f(s);
        p[kn * 4 + r] = e;
        rs_l += e;
      }
    }
#pragma unroll
    for (int i = 0; i < 16; ++i) alkb[i] += d64;

#pragma unroll
    for (int kn = 0; kn < 4; ++kn) {
      U32P a, c;
      a.h[0] = (bf16_t)p[kn * 4 + 0]; a.h[1] = (bf16_t)p[kn * 4 + 1];
      c.h[0] = (bf16_t)p[kn * 4 + 2]; c.h[1] = (bf16_t)p[kn * 4 + 3];
      uint2 pk; pk.x = a.u; pk.y = c.u;
      *(uint2*)&Pl[w][m16 * 72 + kn * 16 + quad * 4] = pk;
    }
    const bf16_t* vt = &Vt[kt & 1][0];
    bf16x8 bp0 = *(const bf16x8*)&Pl[w][m16 * 72 + quad * 8];
    bf16x8 bp1 = *(const bf16x8*)&Pl[w][m16 * 72 + 32 + quad * 8];
#pragma unroll
    for (int ni = 0; ni < 4; ++ni) {
      bf16x8 av0 = *(const bf16x8*)&vt[(ni * 16 + m16) * 72 + quad * 8];
      bf16x8 av1 = *(const bf16x8*)&vt[(ni * 16 + m16) * 72 + 32 + quad * 8];
      acc[ni] = __builtin_amdgcn_mfma_f32_16x16x32_bf16(av0, bp0, acc[ni], 0, 0, 0);
      acc[ni] = __builtin_amdgcn_mfma_f32_16x16x32_bf16(av1, bp1, acc[ni], 0, 0, 0);
    }

    if (kt < qt) {  // stage next V into the other buffer
#pragma unroll
      for (int j = 0; j < 8; ++j) {
        U32P pk; pk.h[0] = nv0[j]; pk.h[1] = nv1[j];
        *(unsigned*)&Vt[(kt + 1) & 1][(vd0 + j) * 72 + kp2] = pk.u;
      }
    }
#pragma unroll
    for (int kn = 0; kn < 4; ++kn) { ak[kn][0] = nk[kn][0]; ak[kn][1] = nk[kn][1]; }
    v0 = nv0; v1 = nv1;
  }

  // epilogue: reduce l across quads (same q = m16 column), then write O
  rs_l += __shfl_xor(rs_l, 16);
  rs_l += __shfl_xor(rs_l, 32);
  const float inv_l = 1.0f / rs_l;
  bf16_t* cb = ctx + (size_t)(b * SS + qt * 64 + w * 16 + m16) * 1024 + h * 64;
#pragma unroll
  for (int ni = 0; ni < 4; ++ni) {
    U32P a, c;
    a.h[0] = (bf16_t)(acc[ni][0] * inv_l); a.h[1] = (bf16_t)(acc[ni][1] * inv_l);
    c.h[0] = (bf16_t)(acc[ni][2] * inv_l); c.h[1] = (bf16_t)(acc[ni][3] * inv_l);
    uint2 pk; pk.x = a.u; pk.y = c.u;
    *(uint2*)(cb + ni * 16 + quad * 4) = pk;
  }
}

// ---------------------------------------------------------------------------
extern "C" void kernel_launch(void* const* d_in, const int* in_sizes, int n_in,
                              void* d_out, int out_size, void* d_ws, size_t ws_size,
                              hipStream_t stream) {
  const float* hs    = (const float*)d_in[0];
  const float* qkvw  = (const float*)d_in[2];
  const float* qkvb  = (const float*)d_in[3];
  const float* dw    = (const float*)d_in[4];
  const float* db    = (const float*)d_in[5];
  const float* w1    = (const float*)d_in[6];
  const float* b1    = (const float*)d_in[7];
  const float* w2    = (const float*)d_in[8];
  const float* b2    = (const float*)d_in[9];
  const float* ln1w  = (const float*)d_in[10];
  const float* ln1b  = (const float*)d_in[11];
  const float* ln2w  = (const float*)d_in[12];
  const float* ln2b  = (const float*)d_in[13];
  float* x = (float*)d_out;  // residual stream, fp32 [4096,1024]

  char* ws = (char*)d_ws;
  bf16_t* wqc = (bf16_t*)(ws + 0);          // 2*3072*1024 bf16
  bf16_t* wdc = (bf16_t*)(ws + 12582912);   // 2*1024*1024
  bf16_t* w1c = (bf16_t*)(ws + 16777216);   // 2*4096*1024
  bf16_t* w2c = (bf16_t*)(ws + 33554432);   // 2*1024*4096
  bf16_t* hb  = (bf16_t*)(ws + 50331648);   // 4096*1024 (ln out / mlp2 partial0)
  bf16_t* qm  = (bf16_t*)(ws + 58720256);   // qkv / mlp-mid / dense partials
  bf16_t* cx  = (bf16_t*)(ws + 92274688);   // 4096*1024 (attn ctx / mlp2 partial1)
  bf16_t* dp0 = qm;                          // dense partials alias qm (free then)
  bf16_t* dp1 = qm + (size_t)4096 * 1024;

  hipMemcpyAsync(x, hs, (size_t)4096 * 1024 * 4, hipMemcpyDeviceToDevice, stream);
  cvt_kernel<<<6144, 256, 0, stream>>>(qkvw, wqc);
  cvt_kernel<<<2048, 256, 0, stream>>>(dw, wdc);
  cvt_kernel<<<8192, 256, 0, stream>>>(w1, w1c);
  cvt_kernel<<<8192, 256, 0, stream>>>(w2, w2c);

  // layer-0 ln1 (subsequent LNs are fused into the residual adds)
  ln_kernel<<<4096, 256, 0, stream>>>(x, ln1w, ln1b, hb);

  for (int l = 0; l < 2; ++l) {
    gemm_bt<0><<<dim3(24, 32), 256, 0, stream>>>(hb, wqc + (size_t)l * 3145728,
        qkvb + l * 3072, qm, 4096, 3072, 1024);
    attn_kernel<<<dim3(32, 32), 256, 0, stream>>>(qm, cx);
    // dense: split-K=2 -> bf16 partials in qm region
    gemm_sk2<<<dim3(8, 32, 2), 256, 0, stream>>>(cx, wdc + (size_t)l * 1048576,
        dp0, dp1, 4096, 1024, 1024);
    // x += dense partials + bias; hb = LN2(x)
    fuse_add_ln<<<4096, 256, 0, stream>>>(x, dp0, dp1, db + l * 1024,
        ln2w + l * 1024, ln2b + l * 1024, hb);
    gemm_bt<1><<<dim3(32, 32), 256, 0, stream>>>(hb, w1c + (size_t)l * 4194304,
        b1 + l * 4096, qm, 4096, 4096, 1024);
    // mlp2: split-K=2 -> partials in hb & cx (both free here)
    gemm_sk2<<<dim3(8, 32, 2), 256, 0, stream>>>(qm, w2c + (size_t)l * 4194304,
        hb, cx, 4096, 1024, 4096);
    if (l == 0) {
      // x += mlp partials + bias; hb = LN1_next(x)
      fuse_add_ln<<<4096, 256, 0, stream>>>(x, hb, cx, b2,
          ln1w + 1024, ln1b + 1024, hb);
    } else {
      fuse_add<<<4096, 256, 0, stream>>>(x, hb, cx, b2 + 1024);
    }
  }
}

// Round 11
// 661.514 us; speedup vs baseline: 1.2213x; 1.0201x over previous
//
#include <hip/hip_runtime.h>
#include <cstdint>
#include <cmath>

#define SS 2048
#define HH 1024

typedef __bf16 bf16_t;
typedef __bf16 bf16x8 __attribute__((ext_vector_type(8)));
typedef __bf16 bf16x4 __attribute__((ext_vector_type(4)));
typedef float  f32x4  __attribute__((ext_vector_type(4)));

union U32P { unsigned u; bf16_t h[2]; };

__device__ __forceinline__ void async_load16(const void* g, void* l) {
  __builtin_amdgcn_global_load_lds(
      (__attribute__((address_space(1))) void*)(g),
      (__attribute__((address_space(3))) void*)(l), 16, 0, 0);
}

// ---------------- fused fp32 -> bf16 convert for all 4 weight tensors -------
// One launch instead of four (saves 3 launch overheads); region by block range.
__global__ __launch_bounds__(256) void cvt_all(const float* __restrict__ s0,
                                               const float* __restrict__ s1,
                                               const float* __restrict__ s2,
                                               const float* __restrict__ s3,
                                               bf16_t* __restrict__ d0,
                                               bf16_t* __restrict__ d1,
                                               bf16_t* __restrict__ d2,
                                               bf16_t* __restrict__ d3) {
  const int blk = blockIdx.x;
  const float* s; bf16_t* d; size_t off;
  if (blk < 6144)       { s = s0; d = d0; off = (size_t)blk * 256; }
  else if (blk < 8192)  { s = s1; d = d1; off = (size_t)(blk - 6144) * 256; }
  else if (blk < 16384) { s = s2; d = d2; off = (size_t)(blk - 8192) * 256; }
  else                  { s = s3; d = d3; off = (size_t)(blk - 16384) * 256; }
  size_t i = off + threadIdx.x;
  f32x4 v = ((const f32x4*)s)[i];
  bf16x4 o;
  o[0] = (bf16_t)v[0]; o[1] = (bf16_t)v[1]; o[2] = (bf16_t)v[2]; o[3] = (bf16_t)v[3];
  ((bf16x4*)d)[i] = o;
}

// ---------------- LayerNorm: fp32 in [4096,1024] -> bf16 out ---------------
__global__ __launch_bounds__(256) void ln_kernel(const float* __restrict__ x,
                                                 const float* __restrict__ w,
                                                 const float* __restrict__ b,
                                                 bf16_t* __restrict__ out) {
  const int row = blockIdx.x;
  const int tid = threadIdx.x;
  const f32x4 v = ((const f32x4*)(x + (size_t)row * HH))[tid];
  float s  = v[0] + v[1] + v[2] + v[3];
  float s2 = v[0]*v[0] + v[1]*v[1] + v[2]*v[2] + v[3]*v[3];
#pragma unroll
  for (int o = 1; o < 64; o <<= 1) { s += __shfl_xor(s, o); s2 += __shfl_xor(s2, o); }
  __shared__ float r1[4], r2[4];
  if ((tid & 63) == 0) { r1[tid >> 6] = s; r2[tid >> 6] = s2; }
  __syncthreads();
  float ts  = r1[0] + r1[1] + r1[2] + r1[3];
  float ts2 = r2[0] + r2[1] + r2[2] + r2[3];
  float mu  = ts * (1.0f / HH);
  float var = ts2 * (1.0f / HH) - mu * mu;
  float rstd = rsqrtf(var + 1e-5f);
  f32x4 wv = ((const f32x4*)w)[tid];
  f32x4 bv = ((const f32x4*)b)[tid];
  bf16x4 o;
#pragma unroll
  for (int j = 0; j < 4; ++j) o[j] = (bf16_t)((v[j] - mu) * rstd * wv[j] + bv[j]);
  ((bf16x4*)(out + (size_t)row * HH))[tid] = o;
}

__device__ __forceinline__ float gelu_f(float x) {
  return 0.5f * x * (1.0f + erff(x * 0.70710678118654752f));
}

// ---- fused residual add: x += p0 + p1 + bias (final use, no trailing LN) ---
__global__ __launch_bounds__(256) void fuse_add(float* __restrict__ x,
                                                const bf16_t* __restrict__ p0,
                                                const bf16_t* __restrict__ p1,
                                                const float* __restrict__ bias) {
  size_t i = (size_t)blockIdx.x * 256 + threadIdx.x;
  f32x4 xv = ((f32x4*)x)[i];
  bf16x4 a = ((const bf16x4*)p0)[i];
  bf16x4 b4 = ((const bf16x4*)p1)[i];
  f32x4 bv = ((const f32x4*)bias)[i & 255];
#pragma unroll
  for (int j = 0; j < 4; ++j) xv[j] += (float)a[j] + (float)b4[j] + bv[j];
  ((f32x4*)x)[i] = xv;
}

// ---- fused residual add + LayerNorm: x += p0+p1+bias; out = LN(x) ----------
__global__ __launch_bounds__(256) void fuse_add_ln(float* __restrict__ x,
                                                   const bf16_t* __restrict__ p0,
                                                   const bf16_t* __restrict__ p1,
                                                   const float* __restrict__ bias,
                                                   const float* __restrict__ lw,
                                                   const float* __restrict__ lb,
                                                   bf16_t* __restrict__ out) {
  const int row = blockIdx.x;
  const int tid = threadIdx.x;
  const size_t i = (size_t)row * 256 + tid;
  f32x4 xv = ((f32x4*)x)[i];
  bf16x4 a = ((const bf16x4*)p0)[i];
  bf16x4 b4 = ((const bf16x4*)p1)[i];
  f32x4 bv = ((const f32x4*)bias)[tid];
#pragma unroll
  for (int j = 0; j < 4; ++j) xv[j] += (float)a[j] + (float)b4[j] + bv[j];
  ((f32x4*)x)[i] = xv;
  float s  = xv[0] + xv[1] + xv[2] + xv[3];
  float s2 = xv[0]*xv[0] + xv[1]*xv[1] + xv[2]*xv[2] + xv[3]*xv[3];
#pragma unroll
  for (int o = 1; o < 64; o <<= 1) { s += __shfl_xor(s, o); s2 += __shfl_xor(s2, o); }
  __shared__ float r1[4], r2[4];
  if ((tid & 63) == 0) { r1[tid >> 6] = s; r2[tid >> 6] = s2; }
  __syncthreads();
  float ts  = r1[0] + r1[1] + r1[2] + r1[3];
  float ts2 = r2[0] + r2[1] + r2[2] + r2[3];
  float mu  = ts * (1.0f / HH);
  float var = ts2 * (1.0f / HH) - mu * mu;
  float rstd = rsqrtf(var + 1e-5f);
  f32x4 wv  = ((const f32x4*)lw)[tid];
  f32x4 lbv = ((const f32x4*)lb)[tid];
  bf16x4 o;
#pragma unroll
  for (int j = 0; j < 4; ++j) o[j] = (bf16_t)((xv[j] - mu) * rstd * wv[j] + lbv[j]);
  ((bf16x4*)(out + (size_t)row * HH))[tid] = o;
}

// ---------------- 2-phase GEMM + XCD-aware block swizzle --------------------
// T1: default dispatch round-robins consecutive blocks (which share an
// A-panel) across the 8 XCDs => every panel fetched 8x through L3. Bijective
// chunked swizzle (nwg%8==0 for all our grids) gives each XCD a contiguous
// run of logical tiles => panels become XCD-L2-resident.
// EPI: 0 = bias; 1 = bias + exact gelu.
template <int EPI>
__global__ __launch_bounds__(256) void gemm_bt(const bf16_t* __restrict__ A,
                                               const bf16_t* __restrict__ W,
                                               const float* __restrict__ bias,
                                               bf16_t* __restrict__ outb,
                                               int M, int N, int K) {
  __shared__ __align__(16) bf16_t As[2][128 * 64];
  __shared__ __align__(16) bf16_t Bs[2][128 * 64];
  const int tid = threadIdx.x;
  const int w = tid >> 6, lane = tid & 63;
  const int m16 = lane & 15, quad = lane >> 4;
  const int wm = w & 1, wn = w >> 1;
  // XCD swizzle: hw block b -> logical tile swz (contiguous chunk per XCD)
  const int nwg = gridDim.x * gridDim.y;
  const int bid = blockIdx.y * gridDim.x + blockIdx.x;
  const int swz = (bid & 7) * (nwg >> 3) + (bid >> 3);
  const int n0 = (swz % gridDim.x) * 128, m0 = (swz / gridDim.x) * 128;

  f32x4 acc[4][4];
#pragma unroll
  for (int i = 0; i < 4; ++i)
#pragma unroll
    for (int j = 0; j < 4; ++j) acc[i][j] = (f32x4){0.f, 0.f, 0.f, 0.f};

  int rowi[4], gci[4];
#pragma unroll
  for (int i = 0; i < 4; ++i) {
    int p = (w * 4 + i) * 64 + lane;
    rowi[i] = p >> 3;
    gci[i] = ((lane & 7) ^ (rowi[i] & 7)) * 8;
  }

  // prologue: stage tile 0 -> buf 0
#pragma unroll
  for (int i = 0; i < 4; ++i) {
    async_load16(A + (size_t)(m0 + rowi[i]) * K + gci[i], &As[0][(w * 4 + i) * 512]);
    async_load16(W + (size_t)(n0 + rowi[i]) * K + gci[i], &Bs[0][(w * 4 + i) * 512]);
  }

  const int NT = K >> 6;
  for (int t = 0; t < NT; ++t) {
    const int cur = t & 1;
    __syncthreads();   // vmcnt(0) drain: tile t resident; buf cur^1 free
    if (t + 1 < NT) {
      const int kt = (t + 1) << 6;
#pragma unroll
      for (int i = 0; i < 4; ++i) {
        async_load16(A + (size_t)(m0 + rowi[i]) * K + kt + gci[i],
                     &As[cur ^ 1][(w * 4 + i) * 512]);
        async_load16(W + (size_t)(n0 + rowi[i]) * K + kt + gci[i],
                     &Bs[cur ^ 1][(w * 4 + i) * 512]);
      }
    }
#pragma unroll
    for (int kk = 0; kk < 2; ++kk) {
      bf16x8 af[4], bfv[4];
#pragma unroll
      for (int mi = 0; mi < 4; ++mi) {
        int row = wm * 64 + mi * 16 + m16;
        int cpos = (kk * 4 + quad) ^ (row & 7);
        af[mi] = *(const bf16x8*)&As[cur][row * 64 + cpos * 8];
      }
#pragma unroll
      for (int ni = 0; ni < 4; ++ni) {
        int row = wn * 64 + ni * 16 + m16;
        int cpos = (kk * 4 + quad) ^ (row & 7);
        bfv[ni] = *(const bf16x8*)&Bs[cur][row * 64 + cpos * 8];
      }
#pragma unroll
      for (int mi = 0; mi < 4; ++mi)
#pragma unroll
        for (int ni = 0; ni < 4; ++ni)
          acc[mi][ni] = __builtin_amdgcn_mfma_f32_16x16x32_bf16(af[mi], bfv[ni],
                                                                acc[mi][ni], 0, 0, 0);
    }
  }

#pragma unroll
  for (int ni = 0; ni < 4; ++ni) {
    int col = n0 + wn * 64 + ni * 16 + m16;
    float bv = bias[col];
#pragma unroll
    for (int mi = 0; mi < 4; ++mi) {
      int rowb = m0 + wm * 64 + mi * 16 + quad * 4;
#pragma unroll
      for (int r = 0; r < 4; ++r) {
        size_t idx = (size_t)(rowb + r) * N + col;
        float v = acc[mi][ni][r] + bv;
        if constexpr (EPI == 1) v = gelu_f(v);
        outb[idx] = (bf16_t)v;
      }
    }
  }
}

// ---- 2-phase split-K=2 GEMM + XCD swizzle: z-th K-half -> bf16 partial -----
__global__ __launch_bounds__(256) void gemm_sk2(const bf16_t* __restrict__ A,
                                                const bf16_t* __restrict__ W,
                                                bf16_t* __restrict__ p0,
                                                bf16_t* __restrict__ p1,
                                                int M, int N, int K) {
  __shared__ __align__(16) bf16_t As[2][128 * 64];
  __shared__ __align__(16) bf16_t Bs[2][128 * 64];
  const int tid = threadIdx.x;
  const int w = tid >> 6, lane = tid & 63;
  const int m16 = lane & 15, quad = lane >> 4;
  const int wm = w & 1, wn = w >> 1;
  // XCD swizzle over the full 3D grid (nwg = 8*32*2 = 512, %8==0)
  const int nwg = gridDim.x * gridDim.y * gridDim.z;
  const int bid = (blockIdx.z * gridDim.y + blockIdx.y) * gridDim.x + blockIdx.x;
  const int swz = (bid & 7) * (nwg >> 3) + (bid >> 3);
  const int bx = swz % gridDim.x;
  const int by = (swz / gridDim.x) % gridDim.y;
  const int z  = swz / (gridDim.x * gridDim.y);
  const int n0 = bx * 128, m0 = by * 128;
  const int kbeg = z * (K >> 1);
  bf16_t* outb = z ? p1 : p0;

  f32x4 acc[4][4];
#pragma unroll
  for (int i = 0; i < 4; ++i)
#pragma unroll
    for (int j = 0; j < 4; ++j) acc[i][j] = (f32x4){0.f, 0.f, 0.f, 0.f};

  int rowi[4], gci[4];
#pragma unroll
  for (int i = 0; i < 4; ++i) {
    int p = (w * 4 + i) * 64 + lane;
    rowi[i] = p >> 3;
    gci[i] = ((lane & 7) ^ (rowi[i] & 7)) * 8;
  }

  // prologue: stage tile kbeg -> buf 0
#pragma unroll
  for (int i = 0; i < 4; ++i) {
    async_load16(A + (size_t)(m0 + rowi[i]) * K + kbeg + gci[i], &As[0][(w * 4 + i) * 512]);
    async_load16(W + (size_t)(n0 + rowi[i]) * K + kbeg + gci[i], &Bs[0][(w * 4 + i) * 512]);
  }

  const int NT = K >> 7;   // (K/2)/64 tiles
  for (int t = 0; t < NT; ++t) {
    const int cur = t & 1;
    __syncthreads();
    if (t + 1 < NT) {
      const int kt = kbeg + ((t + 1) << 6);
#pragma unroll
      for (int i = 0; i < 4; ++i) {
        async_load16(A + (size_t)(m0 + rowi[i]) * K + kt + gci[i],
                     &As[cur ^ 1][(w * 4 + i) * 512]);
        async_load16(W + (size_t)(n0 + rowi[i]) * K + kt + gci[i],
                     &Bs[cur ^ 1][(w * 4 + i) * 512]);
      }
    }
#pragma unroll
    for (int kk = 0; kk < 2; ++kk) {
      bf16x8 af[4], bfv[4];
#pragma unroll
      for (int mi = 0; mi < 4; ++mi) {
        int row = wm * 64 + mi * 16 + m16;
        int cpos = (kk * 4 + quad) ^ (row & 7);
        af[mi] = *(const bf16x8*)&As[cur][row * 64 + cpos * 8];
      }
#pragma unroll
      for (int ni = 0; ni < 4; ++ni) {
        int row = wn * 64 + ni * 16 + m16;
        int cpos = (kk * 4 + quad) ^ (row & 7);
        bfv[ni] = *(const bf16x8*)&Bs[cur][row * 64 + cpos * 8];
      }
#pragma unroll
      for (int mi = 0; mi < 4; ++mi)
#pragma unroll
        for (int ni = 0; ni < 4; ++ni)
          acc[mi][ni] = __builtin_amdgcn_mfma_f32_16x16x32_bf16(af[mi], bfv[ni],
                                                                acc[mi][ni], 0, 0, 0);
    }
  }

#pragma unroll
  for (int ni = 0; ni < 4; ++ni) {
    int col = n0 + wn * 64 + ni * 16 + m16;
#pragma unroll
    for (int mi = 0; mi < 4; ++mi) {
      int rowb = m0 + wm * 64 + mi * 16 + quad * 4;
#pragma unroll
      for (int r = 0; r < 4; ++r) {
        size_t idx = (size_t)(rowb + r) * N + col;
        outb[idx] = (bf16_t)acc[mi][ni][r];
      }
    }
  }
}

// ---------------- Flash attention (round-0 verbatim): analytic max ----------
// Kept: six structural variants all measured >= this version's 90.6us.
__global__ __launch_bounds__(256) void attn_kernel(const bf16_t* __restrict__ qkv,
                                                   bf16_t* __restrict__ ctx) {
  const int qt = 31 - blockIdx.y;   // heavy q-tiles first
  const int bh = blockIdx.x;        // b*16 + h
  const int b = bh >> 4, h = bh & 15;
  const int tid = threadIdx.x;
  const int w = tid >> 6, lane = tid & 63;
  const int m16 = lane & 15, quad = lane >> 4;

  __shared__ __align__(16) bf16_t Vt[2][64 * 72];  // [buf][d][key], pad 8
  __shared__ __align__(16) bf16_t Pl[4][16 * 72];  // per-wave P[q][key], pad 8

  const float slope2 = __builtin_amdgcn_exp2f(-0.70710678118654752f * (float)(h + 1))
                       * 1.4426950408889634f;  // slope_h * log2(e)
  // ALiBi window (tiles): keep tile iff slope2*((qt-kt)*64-63) <= 30
  const int wt = (int)((30.0f / slope2 + 63.0f) * 0.015625f);
  const int kt0 = (qt - wt > 0) ? (qt - wt) : 0;

  const int q_abs = qt * 64 + w * 16 + m16;  // this lane's query position
  float alkb[16];
#pragma unroll
  for (int kn = 0; kn < 4; ++kn)
#pragma unroll
    for (int r = 0; r < 4; ++r)
      alkb[kn * 4 + r] = slope2 * (float)(kt0 * 64 + kn * 16 + quad * 4 + r - q_abs);
  const float d64 = slope2 * 64.0f;

  const int qrow = qt * 64 + w * 16 + m16;
  const bf16_t* qbase = qkv + (size_t)(b * SS + qrow) * 3072 + h * 64;
  const bf16x8 bq0 = *(const bf16x8*)(qbase + quad * 8);
  const bf16x8 bq1 = *(const bf16x8*)(qbase + 32 + quad * 8);

  const bf16_t* kbase = qkv + (size_t)(b * SS + m16) * 3072 + 1024 + h * 64 + quad * 8;
  const int kp2 = (tid & 31) * 2, vd0 = (tid >> 5) * 8;
  const bf16_t* vsrc = qkv + (size_t)(b * SS + kp2) * 3072 + 2048 + h * 64 + vd0;
  const int ql = w * 16 + m16;
  constexpr float C = 0.18033688011112042f;  // log2(e)/8

  f32x4 acc[4];
#pragma unroll
  for (int i = 0; i < 4; ++i) acc[i] = (f32x4){0.f, 0.f, 0.f, 0.f};
  float rs_l = 0.f;  // per-lane partial of l (reduced across quads at end)

  // preload tile kt0: K frags + V staging regs; pre-store V (seen at 1st barrier)
  bf16x8 ak[4][2], v0, v1;
  {
    const bf16_t* kb = kbase + (size_t)kt0 * 64 * 3072;
#pragma unroll
    for (int kn = 0; kn < 4; ++kn) {
      ak[kn][0] = *(const bf16x8*)(kb + (size_t)(kn * 16) * 3072);
      ak[kn][1] = *(const bf16x8*)(kb + (size_t)(kn * 16) * 3072 + 32);
    }
    const bf16_t* vs = vsrc + (size_t)kt0 * 64 * 3072;
    v0 = *(const bf16x8*)(vs);
    v1 = *(const bf16x8*)(vs + 3072);
  }
#pragma unroll
  for (int j = 0; j < 8; ++j) {
    U32P pk; pk.h[0] = v0[j]; pk.h[1] = v1[j];
    *(unsigned*)&Vt[kt0 & 1][(vd0 + j) * 72 + kp2] = pk.u;
  }

  for (int kt = kt0; kt <= qt; ++kt) {
    __syncthreads();  // Vt[kt&1] writes now visible

    bf16x8 nk[4][2], nv0 = v0, nv1 = v1;
    if (kt < qt) {  // issue next-tile loads; consumed a full tile later
      const bf16_t* kb = kbase + (size_t)(kt + 1) * 64 * 3072;
#pragma unroll
      for (int kn = 0; kn < 4; ++kn) {
        nk[kn][0] = *(const bf16x8*)(kb + (size_t)(kn * 16) * 3072);
        nk[kn][1] = *(const bf16x8*)(kb + (size_t)(kn * 16) * 3072 + 32);
      }
      const bf16_t* nsrc = vsrc + (size_t)(kt + 1) * 64 * 3072;
      nv0 = *(const bf16x8*)(nsrc);
      nv1 = *(const bf16x8*)(nsrc + 3072);
    } else {
#pragma unroll
      for (int kn = 0; kn < 4; ++kn) { nk[kn][0] = ak[kn][0]; nk[kn][1] = ak[kn][1]; }
    }

    // S^T tile from pre-loaded K regs; softmax with analytic max (no shuffles)
    float p[16];
    const bool diag = (kt == qt);
#pragma unroll
    for (int kn = 0; kn < 4; ++kn) {
      f32x4 z = (f32x4){0.f, 0.f, 0.f, 0.f};
      z = __builtin_amdgcn_mfma_f32_16x16x32_bf16(ak[kn][0], bq0, z, 0, 0, 0);
      z = __builtin_amdgcn_mfma_f32_16x16x32_bf16(ak[kn][1], bq1, z, 0, 0, 0);
#pragma unroll
      for (int r = 0; r < 4; ++r) {
        float s = fmaf(z[r], C, alkb[kn * 4 + r]);
        if (diag) {
          int kl = kn * 16 + quad * 4 + r;
          if (kl > ql) s = -INFINITY;
        }
        float e = __builtin_amdgcn_exp2f(s);
        p[kn * 4 + r] = e;
        rs_l += e;
      }
    }
#pragma unroll
    for (int i = 0; i < 16; ++i) alkb[i] += d64;

#pragma unroll
    for (int kn = 0; kn < 4; ++kn) {
      U32P a, c;
      a.h[0] = (bf16_t)p[kn * 4 + 0]; a.h[1] = (bf16_t)p[kn * 4 + 1];
      c.h[0] = (bf16_t)p[kn * 4 + 2]; c.h[1] = (bf16_t)p[kn * 4 + 3];
      uint2 pk; pk.x = a.u; pk.y = c.u;
      *(uint2*)&Pl[w][m16 * 72 + kn * 16 + quad * 4] = pk;
    }
    const bf16_t* vt = &Vt[kt & 1][0];
    bf16x8 bp0 = *(const bf16x8*)&Pl[w][m16 * 72 + quad * 8];
    bf16x8 bp1 = *(const bf16x8*)&Pl[w][m16 * 72 + 32 + quad * 8];
#pragma unroll
    for (int ni = 0; ni < 4; ++ni) {
      bf16x8 av0 = *(const bf16x8*)&vt[(ni * 16 + m16) * 72 + quad * 8];
      bf16x8 av1 = *(const bf16x8*)&vt[(ni * 16 + m16) * 72 + 32 + quad * 8];
      acc[ni] = __builtin_amdgcn_mfma_f32_16x16x32_bf16(av0, bp0, acc[ni], 0, 0, 0);
      acc[ni] = __builtin_amdgcn_mfma_f32_16x16x32_bf16(av1, bp1, acc[ni], 0, 0, 0);
    }

    if (kt < qt) {  // stage next V into the other buffer
#pragma unroll
      for (int j = 0; j < 8; ++j) {
        U32P pk; pk.h[0] = nv0[j]; pk.h[1] = nv1[j];
        *(unsigned*)&Vt[(kt + 1) & 1][(vd0 + j) * 72 + kp2] = pk.u;
      }
    }
#pragma unroll
    for (int kn = 0; kn < 4; ++kn) { ak[kn][0] = nk[kn][0]; ak[kn][1] = nk[kn][1]; }
    v0 = nv0; v1 = nv1;
  }

  // epilogue: reduce l across quads (same q = m16 column), then write O
  rs_l += __shfl_xor(rs_l, 16);
  rs_l += __shfl_xor(rs_l, 32);
  const float inv_l = 1.0f / rs_l;
  bf16_t* cb = ctx + (size_t)(b * SS + qt * 64 + w * 16 + m16) * 1024 + h * 64;
#pragma unroll
  for (int ni = 0; ni < 4; ++ni) {
    U32P a, c;
    a.h[0] = (bf16_t)(acc[ni][0] * inv_l); a.h[1] = (bf16_t)(acc[ni][1] * inv_l);
    c.h[0] = (bf16_t)(acc[ni][2] * inv_l); c.h[1] = (bf16_t)(acc[ni][3] * inv_l);
    uint2 pk; pk.x = a.u; pk.y = c.u;
    *(uint2*)(cb + ni * 16 + quad * 4) = pk;
  }
}

// ---------------------------------------------------------------------------
extern "C" void kernel_launch(void* const* d_in, const int* in_sizes, int n_in,
                              void* d_out, int out_size, void* d_ws, size_t ws_size,
                              hipStream_t stream) {
  const float* hs    = (const float*)d_in[0];
  const float* qkvw  = (const float*)d_in[2];
  const float* qkvb  = (const float*)d_in[3];
  const float* dw    = (const float*)d_in[4];
  const float* db    = (const float*)d_in[5];
  const float* w1    = (const float*)d_in[6];
  const float* b1    = (const float*)d_in[7];
  const float* w2    = (const float*)d_in[8];
  const float* b2    = (const float*)d_in[9];
  const float* ln1w  = (const float*)d_in[10];
  const float* ln1b  = (const float*)d_in[11];
  const float* ln2w  = (const float*)d_in[12];
  const float* ln2b  = (const float*)d_in[13];
  float* x = (float*)d_out;  // residual stream, fp32 [4096,1024]

  char* ws = (char*)d_ws;
  bf16_t* wqc = (bf16_t*)(ws + 0);          // 2*3072*1024 bf16
  bf16_t* wdc = (bf16_t*)(ws + 12582912);   // 2*1024*1024
  bf16_t* w1c = (bf16_t*)(ws + 16777216);   // 2*4096*1024
  bf16_t* w2c = (bf16_t*)(ws + 33554432);   // 2*1024*4096
  bf16_t* hb  = (bf16_t*)(ws + 50331648);   // 4096*1024 (ln out / mlp2 partial0)
  bf16_t* qm  = (bf16_t*)(ws + 58720256);   // qkv / mlp-mid / dense partials
  bf16_t* cx  = (bf16_t*)(ws + 92274688);   // 4096*1024 (attn ctx / mlp2 partial1)
  bf16_t* dp0 = qm;                          // dense partials alias qm (free then)
  bf16_t* dp1 = qm + (size_t)4096 * 1024;

  hipMemcpyAsync(x, hs, (size_t)4096 * 1024 * 4, hipMemcpyDeviceToDevice, stream);
  cvt_all<<<24576, 256, 0, stream>>>(qkvw, dw, w1, w2, wqc, wdc, w1c, w2c);

  // layer-0 ln1 (subsequent LNs are fused into the residual adds)
  ln_kernel<<<4096, 256, 0, stream>>>(x, ln1w, ln1b, hb);

  for (int l = 0; l < 2; ++l) {
    gemm_bt<0><<<dim3(24, 32), 256, 0, stream>>>(hb, wqc + (size_t)l * 3145728,
        qkvb + l * 3072, qm, 4096, 3072, 1024);
    attn_kernel<<<dim3(32, 32), 256, 0, stream>>>(qm, cx);
    // dense: split-K=2 -> bf16 partials in qm region
    gemm_sk2<<<dim3(8, 32, 2), 256, 0, stream>>>(cx, wdc + (size_t)l * 1048576,
        dp0, dp1, 4096, 1024, 1024);
    // x += dense partials + bias; hb = LN2(x)
    fuse_add_ln<<<4096, 256, 0, stream>>>(x, dp0, dp1, db + l * 1024,
        ln2w + l * 1024, ln2b + l * 1024, hb);
    gemm_bt<1><<<dim3(32, 32), 256, 0, stream>>>(hb, w1c + (size_t)l * 4194304,
        b1 + l * 4096, qm, 4096, 4096, 1024);
    // mlp2: split-K=2 -> partials in hb & cx (both free here)
    gemm_sk2<<<dim3(8, 32, 2), 256, 0, stream>>>(qm, w2c + (size_t)l * 4194304,
        hb, cx, 4096, 1024, 4096);
    if (l == 0) {
      // x += mlp partials + bias; hb = LN1_next(x)
      fuse_add_ln<<<4096, 256, 0, stream>>>(x, hb, cx, b2,
          ln1w + 1024, ln1b + 1024, hb);
    } else {
      fuse_add<<<4096, 256, 0, stream>>>(x, hb, cx, b2 + 1024);
    }
  }
}